// Round 4
// baseline (1919.479 us; speedup 1.0000x reference)
//
#include <hip/hip_runtime.h>

// MSSFM — naive fp32 correctness anchor (round 4).
// No MFMA, no LDS, no bf16, no d_ws. All intermediates in static device
// globals, NCHW layout everywhere, weights read directly from d_in.
// Diagnostic: if (and only if) d_out ends up with non-finite values, it is
// overwritten with 20000 + 100*flags  (1=y1, 2=t/p, 4=Z/sig, 8=F, 16=q, 32=out)
// so the reported absmax error localizes the first broken stage.

constexpr int kHW = 16384;   // 128*128

__device__ float g_y1f[8388608];   // y1  [b][c][hw]
__device__ float g_t  [8388608];   // tanh tmp, later p
__device__ float g_Zf [8388608];   // Z, then sigmoid(y2) in place
__device__ float g_Ff [8388608];   // F
__device__ float g_q  [16777216];  // q [b][256][hw]
__device__ unsigned g_flag[1];

// buffer selectors for template-parameterized kernels
#define BUF_Y1 0
#define BUF_T  1
#define BUF_Z  2
#define BUF_F  3
#define BUF_Q  4

__device__ __forceinline__ float* bufp(int sel)
{
    switch (sel) {
        case BUF_Y1: return g_y1f;
        case BUF_T:  return g_t;
        case BUF_Z:  return g_Zf;
        case BUF_F:  return g_Ff;
        default:     return g_q;
    }
}

__global__ void k_zero() { g_flag[0] = 0u; }

// ---------------- DPB: dilated 3x3 convs (dil 1 and 7) + PReLU + sum --------
__global__ __launch_bounds__(256) void k_dpb(
    const float* __restrict__ x, const float* __restrict__ d1w,
    const float* __restrict__ d1b, const float* __restrict__ d4w,
    const float* __restrict__ d4b, const float* __restrict__ pa)
{
    int hw = blockIdx.x * 256 + threadIdx.x;
    int c = blockIdx.y, b = blockIdx.z;
    int h = hw >> 7, w = hw & 127;
    float a1 = d1b[c], a4 = d4b[c];
    for (int s = 0; s < 8; ++s) {
        const float* xs = x + (size_t)(b * 8 + s) * kHW;
        const float* w1 = d1w + (c * 8 + s) * 9;
        const float* w4 = d4w + (c * 8 + s) * 9;
        for (int kh = 0; kh < 3; ++kh)
            for (int kw = 0; kw < 3; ++kw) {
                float wv1 = w1[kh * 3 + kw];
                float wv4 = w4[kh * 3 + kw];
                int h1 = h + kh - 1, w1i = w + kw - 1;
                if ((unsigned)h1 < 128u && (unsigned)w1i < 128u)
                    a1 += wv1 * xs[h1 * 128 + w1i];
                int h7 = h + (kh - 1) * 7, w7 = w + (kw - 1) * 7;
                if ((unsigned)h7 < 128u && (unsigned)w7 < 128u)
                    a4 += wv4 * xs[h7 * 128 + w7];
            }
    }
    float p = pa[0];
    a1 = (a1 >= 0.f) ? a1 : p * a1;
    a4 = (a4 >= 0.f) ? a4 : p * a4;
    g_y1f[(size_t)(b * 128 + c) * kHW + hw] = a1 + a4;
}

// ---------------- generic 1x1 conv between device-global buffers ------------
// out[b][c][hw] = ACT( bias[c] + sum_k W[c][k] * in[b][k][hw] )
// ACT: 0 none, 1 tanh, 2 sigmoid, 3 gelu(exact)
template <int INSEL, int OUTSEL, int K, int M, int ACT>
__global__ __launch_bounds__(256) void k_c1(const float* __restrict__ W,
                                            const float* __restrict__ bias)
{
    int hw = blockIdx.x * 256 + threadIdx.x;
    int c = blockIdx.y, b = blockIdx.z;
    const float* in = bufp(INSEL);
    float* out = bufp(OUTSEL);
    float acc = bias[c];
    const float* wr = W + (size_t)c * K;
    const float* ip = in + (size_t)b * K * kHW + hw;
    for (int k = 0; k < K; ++k)
        acc += wr[k] * ip[(size_t)k * kHW];
    if (ACT == 1)      acc = tanhf(acc);
    else if (ACT == 2) acc = 1.f / (1.f + expf(-acc));
    else if (ACT == 3) acc = 0.5f * acc * (1.f + erff(acc * 0.70710678118f));
    out[((size_t)b * M + c) * kHW + hw] = acc;
}

// ---------------- PSA gate: p = (conv(y1,pw3)+pb3)*y1 + y1 -> g_t -----------
__global__ __launch_bounds__(256) void k_pmul(const float* __restrict__ W,
                                              const float* __restrict__ bias)
{
    int hw = blockIdx.x * 256 + threadIdx.x;
    int c = blockIdx.y, b = blockIdx.z;
    float acc = bias[c];
    const float* wr = W + (size_t)c * 128;
    const float* ip = g_y1f + (size_t)b * 128 * kHW + hw;
    for (int k = 0; k < 128; ++k)
        acc += wr[k] * ip[(size_t)k * kHW];
    size_t i = (size_t)(b * 128 + c) * kHW + hw;
    float y = g_y1f[i];
    g_t[i] = acc * y + y;
}

// ---------------- SRU scan over H; sigmoid(y2) in place into g_Zf -----------
// c<64: reverse scan y2[h] = f[h]*y2[h+1] + (1-f[h])*z[h]
// c>=64: forward scan (flip(reverse(flip)) algebra)
__global__ __launch_bounds__(256) void k_scan()
{
    int b = blockIdx.x >> 6;
    int c = ((blockIdx.x & 63) << 1) + (threadIdx.x >> 7);
    int w = threadIdx.x & 127;
    size_t base = (size_t)(b * 128 + c) * kHW + w;
    float st = 0.f;
    if (c < 64) {
        for (int h = 127; h >= 0; --h) {
            size_t i = base + h * 128;
            float z = g_Zf[i], f = g_Ff[i];
            st = f * st + (1.f - f) * z;
            g_Zf[i] = 1.f / (1.f + expf(-st));
        }
    } else {
        for (int h = 0; h < 128; ++h) {
            size_t i = base + h * 128;
            float z = g_Zf[i], f = g_Ff[i];
            st = f * st + (1.f - f) * z;
            g_Zf[i] = 1.f / (1.f + expf(-st));
        }
    }
}

// ---------------- final: out = conv(q,pw2)+pb2 + y1*sig ---------------------
__global__ __launch_bounds__(256) void k_final(const float* __restrict__ W,
                                               const float* __restrict__ bias,
                                               float* __restrict__ out)
{
    int hw = blockIdx.x * 256 + threadIdx.x;
    int c = blockIdx.y, b = blockIdx.z;
    float acc = bias[c];
    const float* wr = W + (size_t)c * 256;
    const float* ip = g_q + (size_t)b * 256 * kHW + hw;
    for (int k = 0; k < 256; ++k)
        acc += wr[k] * ip[(size_t)k * kHW];
    size_t i = (size_t)(b * 128 + c) * kHW + hw;
    out[i] = acc + g_y1f[i] * g_Zf[i];
}

// ---------------- diagnostics ----------------------------------------------
__device__ __forceinline__ bool badf(float v) { return !(fabsf(v) <= 1e30f); }

__global__ __launch_bounds__(256) void k_diag(const float* __restrict__ out)
{
    size_t i = (size_t)blockIdx.x * 256 + threadIdx.x;  // 0..16.7M
    unsigned f = 0;
    if (i < 8388608u) {
        if (badf(g_y1f[i])) f |= 1u;
        if (badf(g_t[i]))   f |= 2u;
        if (badf(g_Zf[i]))  f |= 4u;
        if (badf(g_Ff[i]))  f |= 8u;
        if (badf(out[i]))   f |= 32u;
    }
    if (i < 16777216u && badf(g_q[i])) f |= 16u;
    if (f) atomicOr(&g_flag[0], f);
}

__global__ __launch_bounds__(256) void k_fix(float* __restrict__ out)
{
    unsigned fl = g_flag[0];
    if (!(fl & 32u)) return;   // output finite -> leave untouched
    size_t i = (size_t)blockIdx.x * 256 + threadIdx.x;
    if (i < 8388608u) out[i] = 20000.f + 100.f * (float)fl;
}

// ---------------------------------------------------------------------------
extern "C" void kernel_launch(void* const* d_in, const int* in_sizes, int n_in,
                              void* d_out, int out_size, void* d_ws, size_t ws_size,
                              hipStream_t stream)
{
    const float* x    = (const float*)d_in[0];
    const float* d1w  = (const float*)d_in[1];
    const float* d1b  = (const float*)d_in[2];
    const float* d4w  = (const float*)d_in[3];
    const float* d4b  = (const float*)d_in[4];
    const float* pa   = (const float*)d_in[5];
    const float* f1w1 = (const float*)d_in[6];
    const float* f1b1 = (const float*)d_in[7];
    const float* f1w2 = (const float*)d_in[8];
    const float* f1b2 = (const float*)d_in[9];
    const float* f2w1 = (const float*)d_in[10];
    const float* f2b1 = (const float*)d_in[11];
    const float* f2w2 = (const float*)d_in[12];
    const float* f2b2 = (const float*)d_in[13];
    const float* pw1  = (const float*)d_in[14];
    const float* pb1  = (const float*)d_in[15];
    const float* pw2  = (const float*)d_in[16];
    const float* pb2  = (const float*)d_in[17];
    const float* pw3  = (const float*)d_in[18];
    const float* pb3  = (const float*)d_in[19];
    float* out = (float*)d_out;

    const dim3 g128(64, 128, 4), g256(64, 256, 4);

    k_zero<<<1, 1, 0, stream>>>();
    k_dpb<<<g128, 256, 0, stream>>>(x, d1w, d1b, d4w, d4b, pa);

    // MHSA pre-scan
    k_c1<BUF_Y1, BUF_T, 128, 128, 1><<<g128, 256, 0, stream>>>(f1w1, f1b1);
    k_c1<BUF_T,  BUF_Z, 128, 128, 1><<<g128, 256, 0, stream>>>(f1w2, f1b2);
    k_c1<BUF_Y1, BUF_T, 128, 128, 1><<<g128, 256, 0, stream>>>(f2w1, f2b1);
    k_c1<BUF_T,  BUF_F, 128, 128, 2><<<g128, 256, 0, stream>>>(f2w2, f2b2);
    k_scan<<<256, 256, 0, stream>>>();

    // PSA
    k_pmul<<<g128, 256, 0, stream>>>(pw3, pb3);
    k_c1<BUF_T, BUF_Q, 128, 256, 3><<<g256, 256, 0, stream>>>(pw1, pb1);
    k_final<<<g128, 256, 0, stream>>>(pw2, pb2, out);

    // diagnose + (conditionally) encode
    k_diag<<<65536, 256, 0, stream>>>(out);
    k_fix<<<32768, 256, 0, stream>>>(out);

    (void)in_sizes; (void)n_in; (void)d_ws; (void)ws_size; (void)out_size;
}

// Round 5
// 657.477 us; speedup vs baseline: 2.9195x; 2.9195x over previous
//
#include <hip/hip_runtime.h>

// MSSFM round 5 — hybrid: validated naive stages (k_dpb, k_pmul, k_scan) +
// MFMA GEMM stages (k_prescan: y1->Z,F ; k_mega: p->q->out).
// All inter-kernel interfaces NCHW f32. All LDS <= 64KB. Diag localizer kept:
// if d_out ends non-finite it is rewritten to 20000+100*flags
// (1=y1, 2=p, 4=Z/sig, 8=F, 32=out).

typedef __bf16 bf16x8 __attribute__((ext_vector_type(8)));
typedef __bf16 bf16x4 __attribute__((ext_vector_type(4)));
typedef float  f32x4  __attribute__((ext_vector_type(4)));

constexpr int kHW = 16384;   // 128*128

__device__ float g_y1f[8388608];   // y1 [b][c][hw]
__device__ float g_t  [8388608];   // p  [b][c][hw]
__device__ float g_Zf [8388608];   // Z, then sigmoid(y2) in place
__device__ float g_Ff [8388608];   // F
__device__ __align__(16) __bf16 g_w[131072];  // f1w1@0 f1w2@16384 f2w1@32768
                                              // f2w2@49152 pw1@65536 pw2@98304
__device__ unsigned g_flag[1];

__global__ void k_zero() { g_flag[0] = 0u; }

// ---------------- pack 1x1-conv weights to bf16 -----------------------------
__global__ __launch_bounds__(256) void k_prepw(
    const float* __restrict__ f1w1, const float* __restrict__ f1w2,
    const float* __restrict__ f2w1, const float* __restrict__ f2w2,
    const float* __restrict__ pw1, const float* __restrict__ pw2)
{
    int idx = blockIdx.x * 256 + threadIdx.x;  // 131072
    float v;
    if (idx < 16384)        v = f1w1[idx];
    else if (idx < 32768)   v = f1w2[idx - 16384];
    else if (idx < 49152)   v = f2w1[idx - 32768];
    else if (idx < 65536)   v = f2w2[idx - 49152];
    else if (idx < 98304)   v = pw1[idx - 65536];
    else                    v = pw2[idx - 98304];
    g_w[idx] = (__bf16)v;
}

// ---------------- DPB: dilated 3x3 convs + PReLU + sum (validated r4) -------
__global__ __launch_bounds__(256) void k_dpb(
    const float* __restrict__ x, const float* __restrict__ d1w,
    const float* __restrict__ d1b, const float* __restrict__ d4w,
    const float* __restrict__ d4b, const float* __restrict__ pa)
{
    int hw = blockIdx.x * 256 + threadIdx.x;
    int c = blockIdx.y, b = blockIdx.z;
    int h = hw >> 7, w = hw & 127;
    float a1 = d1b[c], a4 = d4b[c];
    for (int s = 0; s < 8; ++s) {
        const float* xs = x + (size_t)(b * 8 + s) * kHW;
        const float* w1 = d1w + (c * 8 + s) * 9;
        const float* w4 = d4w + (c * 8 + s) * 9;
        for (int kh = 0; kh < 3; ++kh)
            for (int kw = 0; kw < 3; ++kw) {
                float wv1 = w1[kh * 3 + kw];
                float wv4 = w4[kh * 3 + kw];
                int h1 = h + kh - 1, w1i = w + kw - 1;
                if ((unsigned)h1 < 128u && (unsigned)w1i < 128u)
                    a1 += wv1 * xs[h1 * 128 + w1i];
                int h7 = h + (kh - 1) * 7, w7 = w + (kw - 1) * 7;
                if ((unsigned)h7 < 128u && (unsigned)w7 < 128u)
                    a4 += wv4 * xs[h7 * 128 + w7];
            }
    }
    float p = pa[0];
    a1 = (a1 >= 0.f) ? a1 : p * a1;
    a4 = (a4 >= 0.f) ? a4 : p * a4;
    g_y1f[(size_t)(b * 128 + c) * kHW + hw] = a1 + a4;
}

// ---------------- 128x128 MFMA GEMM step over a 64-pixel tile ---------------
// D[n][m] = ACT( sum_k W[m][k]*B[n][k] + bias[m] );  ACT: 0 tanh, 1 sigmoid.
// Output to LDS tile (Tdst) or NCHW f32 global (gdst).
template <int ACT>
__device__ void gemm_step(const __bf16 (*__restrict__ Bsrc)[136],
                          const __bf16* __restrict__ Wg,
                          const float* __restrict__ bias,
                          __bf16 (*__restrict__ Tdst)[136],
                          float* __restrict__ gdst, int b, int hw0,
                          __bf16 (*__restrict__ Ws)[40])
{
    const int tid = threadIdx.x;
    const int lane = tid & 63, wid = tid >> 6;
    const int fr = lane & 15, kg = (lane >> 4) << 3, mrow = (lane >> 4) << 2;

    f32x4 acc[2][4];
#pragma unroll
    for (int mt = 0; mt < 2; ++mt)
#pragma unroll
        for (int nt = 0; nt < 4; ++nt)
#pragma unroll
            for (int r = 0; r < 4; ++r) acc[mt][nt][r] = 0.f;

#pragma unroll
    for (int k0 = 0; k0 < 128; k0 += 32) {
        {
            int m = tid >> 1, ks = (tid & 1) * 16;
            const __bf16* src = Wg + (size_t)m * 128 + k0 + ks;
            *(bf16x8*)&Ws[m][ks]     = *(const bf16x8*)src;
            *(bf16x8*)&Ws[m][ks + 8] = *(const bf16x8*)(src + 8);
        }
        __syncthreads();
        bf16x8 af[2], bfr[4];
#pragma unroll
        for (int mt = 0; mt < 2; ++mt)
            af[mt] = *(const bf16x8*)&Ws[wid * 32 + mt * 16 + fr][kg];
#pragma unroll
        for (int nt = 0; nt < 4; ++nt)
            bfr[nt] = *(const bf16x8*)&Bsrc[nt * 16 + fr][k0 + kg];
#pragma unroll
        for (int mt = 0; mt < 2; ++mt)
#pragma unroll
            for (int nt = 0; nt < 4; ++nt)
                acc[mt][nt] = __builtin_amdgcn_mfma_f32_16x16x32_bf16(af[mt], bfr[nt], acc[mt][nt], 0, 0, 0);
        __syncthreads();
    }

#pragma unroll
    for (int nt = 0; nt < 4; ++nt) {
        int nl = nt * 16 + fr;
#pragma unroll
        for (int mt = 0; mt < 2; ++mt) {
            int m = wid * 32 + mt * 16 + mrow;
            float vv[4];
#pragma unroll
            for (int r = 0; r < 4; ++r) {
                float v = acc[mt][nt][r] + bias[m + r];
                vv[r] = (ACT == 0) ? tanhf(v) : 1.f / (1.f + expf(-v));
            }
            if (Tdst) {
                bf16x4 o;
#pragma unroll
                for (int r = 0; r < 4; ++r) o[r] = (__bf16)vv[r];
                *(bf16x4*)&Tdst[nl][m] = o;
            } else {
#pragma unroll
                for (int r = 0; r < 4; ++r)
                    gdst[(size_t)(b * 128 + m + r) * kHW + hw0 + nl] = vv[r];
            }
        }
    }
}

// ---------------- MHSA pre-scan: y1 -> Z, F (4 chained GEMMs) ---------------
__global__ __launch_bounds__(256) void k_prescan(
    const float* __restrict__ f1b1, const float* __restrict__ f1b2,
    const float* __restrict__ f2b1, const float* __restrict__ f2b2)
{
    __shared__ __bf16 Bt[64][136];
    __shared__ __bf16 Tt[64][136];
    __shared__ __bf16 Ws[128][40];

    const int tid = threadIdx.x;
    const int n0 = blockIdx.x * 64;
    const int b = n0 >> 14, hw0 = n0 & 16383;
    const int nl = tid & 63, wq = tid >> 6;

    // stage y1 tile transposed: Bt[pixel][channel], bf16
    for (int cc = 0; cc < 32; ++cc) {
        int c = wq * 32 + cc;
        Bt[nl][c] = (__bf16)g_y1f[(size_t)(b * 128 + c) * kHW + hw0 + nl];
    }
    __syncthreads();

    gemm_step<0>(Bt, g_w,         f1b1, Tt, nullptr, b, hw0, Ws);
    __syncthreads();
    gemm_step<0>(Tt, g_w + 16384, f1b2, nullptr, g_Zf, b, hw0, Ws);
    __syncthreads();
    gemm_step<0>(Bt, g_w + 32768, f2b1, Tt, nullptr, b, hw0, Ws);
    __syncthreads();
    gemm_step<1>(Tt, g_w + 49152, f2b2, nullptr, g_Ff, b, hw0, Ws);
}

// ---------------- SRU scan over H; sigmoid(y2) in place (validated r4) ------
__global__ __launch_bounds__(256) void k_scan()
{
    int b = blockIdx.x >> 6;
    int c = ((blockIdx.x & 63) << 1) + (threadIdx.x >> 7);
    int w = threadIdx.x & 127;
    size_t base = (size_t)(b * 128 + c) * kHW + w;
    float st = 0.f;
    if (c < 64) {
        for (int h = 127; h >= 0; --h) {
            size_t i = base + h * 128;
            float z = g_Zf[i], f = g_Ff[i];
            st = f * st + (1.f - f) * z;
            g_Zf[i] = 1.f / (1.f + expf(-st));
        }
    } else {
        for (int h = 0; h < 128; ++h) {
            size_t i = base + h * 128;
            float z = g_Zf[i], f = g_Ff[i];
            st = f * st + (1.f - f) * z;
            g_Zf[i] = 1.f / (1.f + expf(-st));
        }
    }
}

// ---------------- PSA gate: p = (conv(y1,pw3)+pb3)*y1 + y1 (validated r4) ---
__global__ __launch_bounds__(256) void k_pmul(const float* __restrict__ W,
                                              const float* __restrict__ bias)
{
    int hw = blockIdx.x * 256 + threadIdx.x;
    int c = blockIdx.y, b = blockIdx.z;
    float acc = bias[c];
    const float* wr = W + (size_t)c * 128;
    const float* ip = g_y1f + (size_t)b * 128 * kHW + hw;
    for (int k = 0; k < 128; ++k)
        acc += wr[k] * ip[(size_t)k * kHW];
    size_t i = (size_t)(b * 128 + c) * kHW + hw;
    float y = g_y1f[i];
    g_t[i] = acc * y + y;
}

// ---------------- mega: p -> q(LDS) -> out  (2 MFMA GEMMs) ------------------
__global__ __launch_bounds__(256) void k_mega(const float* __restrict__ pb1,
                                              const float* __restrict__ pb2,
                                              float* __restrict__ out)
{
    __shared__ __align__(16) char U[33792];    // Pt[64][136] then Qt[64][264]
    __shared__ __bf16 Ws[256][40];
    auto Pt = (__bf16 (*)[136])U;
    auto Qt = (__bf16 (*)[264])U;

    const int tid = threadIdx.x;
    const int n0 = blockIdx.x * 64;
    const int b = n0 >> 14, hw0 = n0 & 16383;
    const int lane = tid & 63, wid = tid >> 6;
    const int fr = lane & 15, kg = (lane >> 4) << 3, mrow = (lane >> 4) << 2;
    const int nl = tid & 63, wq = tid >> 6;

    // stage p tile transposed
    for (int cc = 0; cc < 32; ++cc) {
        int c = wq * 32 + cc;
        Pt[nl][c] = (__bf16)g_t[(size_t)(b * 128 + c) * kHW + hw0 + nl];
    }
    __syncthreads();

    // ---- gemm2: q = gelu(W1[256][128].p + pb1) -> Qt (aliases Pt) ----
    {
        f32x4 acc[4][4];
#pragma unroll
        for (int mt = 0; mt < 4; ++mt)
#pragma unroll
            for (int nt = 0; nt < 4; ++nt)
#pragma unroll
                for (int r = 0; r < 4; ++r) acc[mt][nt][r] = 0.f;
#pragma unroll
        for (int k0 = 0; k0 < 128; k0 += 32) {
            {
                const __bf16* src = g_w + 65536 + (size_t)tid * 128 + k0;
                *(bf16x8*)&Ws[tid][0]  = *(const bf16x8*)src;
                *(bf16x8*)&Ws[tid][8]  = *(const bf16x8*)(src + 8);
                *(bf16x8*)&Ws[tid][16] = *(const bf16x8*)(src + 16);
                *(bf16x8*)&Ws[tid][24] = *(const bf16x8*)(src + 24);
            }
            __syncthreads();
            bf16x8 af[4], bfr[4];
#pragma unroll
            for (int mt = 0; mt < 4; ++mt)
                af[mt] = *(const bf16x8*)&Ws[wid * 64 + mt * 16 + fr][kg];
#pragma unroll
            for (int nt = 0; nt < 4; ++nt)
                bfr[nt] = *(const bf16x8*)&Pt[nt * 16 + fr][k0 + kg];
#pragma unroll
            for (int mt = 0; mt < 4; ++mt)
#pragma unroll
                for (int nt = 0; nt < 4; ++nt)
                    acc[mt][nt] = __builtin_amdgcn_mfma_f32_16x16x32_bf16(af[mt], bfr[nt], acc[mt][nt], 0, 0, 0);
            __syncthreads();
        }
        // all Pt reads done (barrier above) -> safe to overwrite as Qt
#pragma unroll
        for (int nt = 0; nt < 4; ++nt) {
            int nlq = nt * 16 + fr;
#pragma unroll
            for (int mt = 0; mt < 4; ++mt) {
                int m = wid * 64 + mt * 16 + mrow;
                bf16x4 o;
#pragma unroll
                for (int r = 0; r < 4; ++r) {
                    float xx = acc[mt][nt][r] + pb1[m + r];
                    o[r] = (__bf16)(0.5f * xx * (1.f + erff(xx * 0.70710678118f)));
                }
                *(bf16x4*)&Qt[nlq][m] = o;
            }
        }
    }
    __syncthreads();

    // ---- gemm3: out = W2[128][256].q + pb2 + y1*sig  (NCHW f32) ----
    {
        f32x4 acc[2][4];
#pragma unroll
        for (int mt = 0; mt < 2; ++mt)
#pragma unroll
            for (int nt = 0; nt < 4; ++nt)
#pragma unroll
                for (int r = 0; r < 4; ++r) acc[mt][nt][r] = 0.f;
#pragma unroll
        for (int k0 = 0; k0 < 256; k0 += 32) {
            {
                int m = tid >> 1, ks = (tid & 1) * 16;
                const __bf16* src = g_w + 98304 + (size_t)m * 256 + k0 + ks;
                *(bf16x8*)&Ws[m][ks]     = *(const bf16x8*)src;
                *(bf16x8*)&Ws[m][ks + 8] = *(const bf16x8*)(src + 8);
            }
            __syncthreads();
            bf16x8 af[2], bfr[4];
#pragma unroll
            for (int mt = 0; mt < 2; ++mt)
                af[mt] = *(const bf16x8*)&Ws[wid * 32 + mt * 16 + fr][kg];
#pragma unroll
            for (int nt = 0; nt < 4; ++nt)
                bfr[nt] = *(const bf16x8*)&Qt[nt * 16 + fr][k0 + kg];
#pragma unroll
            for (int mt = 0; mt < 2; ++mt)
#pragma unroll
                for (int nt = 0; nt < 4; ++nt)
                    acc[mt][nt] = __builtin_amdgcn_mfma_f32_16x16x32_bf16(af[mt], bfr[nt], acc[mt][nt], 0, 0, 0);
            __syncthreads();
        }
#pragma unroll
        for (int nt = 0; nt < 4; ++nt) {
            int hw = hw0 + nt * 16 + fr;
#pragma unroll
            for (int mt = 0; mt < 2; ++mt) {
                int m = wid * 32 + mt * 16 + mrow;
#pragma unroll
                for (int r = 0; r < 4; ++r) {
                    size_t i = (size_t)(b * 128 + m + r) * kHW + hw;
                    out[i] = acc[mt][nt][r] + pb2[m + r] + g_y1f[i] * g_Zf[i];
                }
            }
        }
    }
}

// ---------------- diagnostics ----------------------------------------------
__device__ __forceinline__ bool badf(float v) { return !(fabsf(v) <= 1e30f); }

__global__ __launch_bounds__(256) void k_diag(const float* __restrict__ out)
{
    size_t i = (size_t)blockIdx.x * 256 + threadIdx.x;  // 8388608
    unsigned f = 0;
    if (badf(g_y1f[i])) f |= 1u;
    if (badf(g_t[i]))   f |= 2u;
    if (badf(g_Zf[i]))  f |= 4u;
    if (badf(g_Ff[i]))  f |= 8u;
    if (badf(out[i]))   f |= 32u;
    if (f) atomicOr(&g_flag[0], f);
}

__global__ __launch_bounds__(256) void k_fix(float* __restrict__ out)
{
    unsigned fl = g_flag[0];
    if (!(fl & 32u)) return;   // output finite -> untouched
    size_t i = (size_t)blockIdx.x * 256 + threadIdx.x;
    out[i] = 20000.f + 100.f * (float)fl;
}

// ---------------------------------------------------------------------------
extern "C" void kernel_launch(void* const* d_in, const int* in_sizes, int n_in,
                              void* d_out, int out_size, void* d_ws, size_t ws_size,
                              hipStream_t stream)
{
    const float* x    = (const float*)d_in[0];
    const float* d1w  = (const float*)d_in[1];
    const float* d1b  = (const float*)d_in[2];
    const float* d4w  = (const float*)d_in[3];
    const float* d4b  = (const float*)d_in[4];
    const float* pa   = (const float*)d_in[5];
    const float* f1w1 = (const float*)d_in[6];
    const float* f1b1 = (const float*)d_in[7];
    const float* f1w2 = (const float*)d_in[8];
    const float* f1b2 = (const float*)d_in[9];
    const float* f2w1 = (const float*)d_in[10];
    const float* f2b1 = (const float*)d_in[11];
    const float* f2w2 = (const float*)d_in[12];
    const float* f2b2 = (const float*)d_in[13];
    const float* pw1  = (const float*)d_in[14];
    const float* pb1  = (const float*)d_in[15];
    const float* pw2  = (const float*)d_in[16];
    const float* pb2  = (const float*)d_in[17];
    const float* pw3  = (const float*)d_in[18];
    const float* pb3  = (const float*)d_in[19];
    float* out = (float*)d_out;

    k_zero<<<1, 1, 0, stream>>>();
    k_prepw<<<512, 256, 0, stream>>>(f1w1, f1w2, f2w1, f2w2, pw1, pw2);
    k_dpb<<<dim3(64, 128, 4), 256, 0, stream>>>(x, d1w, d1b, d4w, d4b, pa);

    k_prescan<<<1024, 256, 0, stream>>>(f1b1, f1b2, f2b1, f2b2);
    k_scan<<<256, 256, 0, stream>>>();

    k_pmul<<<dim3(64, 128, 4), 256, 0, stream>>>(pw3, pb3);
    k_mega<<<1024, 256, 0, stream>>>(pb1, pb2, out);

    k_diag<<<32768, 256, 0, stream>>>(out);
    k_fix<<<32768, 256, 0, stream>>>(out);

    (void)in_sizes; (void)n_in; (void)d_ws; (void)ws_size; (void)out_size;
}

// Round 6
// 272.697 us; speedup vs baseline: 7.0389x; 2.4110x over previous
//
#include <hip/hip_runtime.h>

// MSSFM round 6 — all GEMM-shaped stages on MFMA.
//   k_prepw:   pack 1x1 weights + im2col A1/A4 (+pw3) to bf16
//   k_conv:    DPB dilated 3x3 convs as im2col MFMA GEMMs (LDS 36.9KB)
//   k_prescan: y1 -> Z,F (4 chained GEMMs, validated r5, LDS 45KB)
//   k_scan:    SRU over H (validated r4)
//   k_mega:    pmul GEMM + q GEMM (split-M) + final GEMM (LDS 61.4KB)
// HARD RULE: static LDS per kernel <= 64KB (rounds 1-3 NaN = silent launch
// failure from 80KB/72KB LDS kernels).
// Diag: if d_out non-finite -> out = 20000+100*flags (1=y1,4=Z,8=F,32=out).

typedef __bf16 bf16x8 __attribute__((ext_vector_type(8)));
typedef __bf16 bf16x4 __attribute__((ext_vector_type(4)));
typedef float  f32x4  __attribute__((ext_vector_type(4)));

constexpr int kHW = 16384;   // 128*128

__device__ float g_y1f[8388608];   // y1 [b][c][hw] f32
__device__ float g_Zf [8388608];   // Z, then sigmoid(y2) in place
__device__ float g_Ff [8388608];   // F
// g_w elems: f1w1@0 f1w2@16384 f2w1@32768 f2w2@49152 pw1@65536 pw2@98304
//            A1@131072[128][96] A4@143360[128][96] pw3@155648
__device__ __align__(16) __bf16 g_w[172032];
__device__ unsigned g_flag[1];

__global__ void k_zero() { g_flag[0] = 0u; }

// ---------------- pack weights to bf16 --------------------------------------
__global__ __launch_bounds__(256) void k_prepw(
    const float* __restrict__ f1w1, const float* __restrict__ f1w2,
    const float* __restrict__ f2w1, const float* __restrict__ f2w2,
    const float* __restrict__ pw1, const float* __restrict__ pw2,
    const float* __restrict__ d1w, const float* __restrict__ d4w,
    const float* __restrict__ pw3)
{
    int idx = blockIdx.x * 256 + threadIdx.x;  // 172032
    float v;
    if (idx < 16384)        v = f1w1[idx];
    else if (idx < 32768)   v = f1w2[idx - 16384];
    else if (idx < 49152)   v = f2w1[idx - 32768];
    else if (idx < 65536)   v = f2w2[idx - 49152];
    else if (idx < 98304)   v = pw1[idx - 65536];
    else if (idx < 131072)  v = pw2[idx - 98304];
    else if (idx < 155648) {
        // A1/A4: [128 c][96 k], k = tap*8+s (tap=kh*3+kw), taps 9..11 zero
        int r = idx - 131072;
        const float* src = d1w;
        if (r >= 12288) { r -= 12288; src = d4w; }
        int c = r / 96, k = r - c * 96;
        int tap = k >> 3, s = k & 7;
        v = (tap < 9) ? src[c * 72 + s * 9 + tap] : 0.f;
    } else                  v = pw3[idx - 155648];
    g_w[idx] = (__bf16)v;
}

// ---------------- DPB: dilated 3x3 convs as im2col MFMA GEMMs ---------------
__global__ __launch_bounds__(256) void k_conv(
    const float* __restrict__ x, const float* __restrict__ d1b,
    const float* __restrict__ d4b, const float* __restrict__ pa)
{
    __shared__ __bf16 B1s[64][104];   // 13312 B
    __shared__ __bf16 B4s[64][104];   // 13312 B
    __shared__ __bf16 Ws[128][40];    // 10240 B   -> total 36864 B
    const int tid = threadIdx.x;
    const int n0 = blockIdx.x * 64;
    const int b = n0 >> 14, hw0 = n0 & 16383;

    // assemble im2col tiles (taps 9..11 zero)
    for (int task = tid; task < 768; task += 256) {
        int nl = task & 63, tap = task >> 6;
        int hw = hw0 + nl, h = hw >> 7, w = hw & 127;
        bf16x8 v1, v4;
#pragma unroll
        for (int i = 0; i < 8; ++i) { v1[i] = (__bf16)0.f; v4[i] = (__bf16)0.f; }
        if (tap < 9) {
            int dh = tap / 3 - 1, dw = tap % 3 - 1;
            int h1 = h + dh, w1 = w + dw;
            int h7 = h + dh * 7, w7 = w + dw * 7;
            bool ok1 = (unsigned)h1 < 128u && (unsigned)w1 < 128u;
            bool ok4 = (unsigned)h7 < 128u && (unsigned)w7 < 128u;
#pragma unroll
            for (int s = 0; s < 8; ++s) {
                if (ok1) v1[s] = (__bf16)x[(size_t)(b * 8 + s) * kHW + h1 * 128 + w1];
                if (ok4) v4[s] = (__bf16)x[(size_t)(b * 8 + s) * kHW + h7 * 128 + w7];
            }
        }
        *(bf16x8*)&B1s[nl][tap * 8] = v1;
        *(bf16x8*)&B4s[nl][tap * 8] = v4;
    }

    const int lane = tid & 63, wid = tid >> 6;
    const int fr = lane & 15, kg = (lane >> 4) << 3, mrow = (lane >> 4) << 2;

    f32x4 acc1[2][4], acc4[2][4];
#pragma unroll
    for (int mt = 0; mt < 2; ++mt)
#pragma unroll
        for (int nt = 0; nt < 4; ++nt)
#pragma unroll
            for (int r = 0; r < 4; ++r) { acc1[mt][nt][r] = 0.f; acc4[mt][nt][r] = 0.f; }

#pragma unroll
    for (int cv = 0; cv < 2; ++cv) {
        const __bf16* Ag = g_w + (cv ? 143360 : 131072);
#pragma unroll
        for (int k0 = 0; k0 < 96; k0 += 32) {
            {
                int m = tid >> 1, ks = (tid & 1) * 16;
                const __bf16* src = Ag + (size_t)m * 96 + k0 + ks;
                *(bf16x8*)&Ws[m][ks]     = *(const bf16x8*)src;
                *(bf16x8*)&Ws[m][ks + 8] = *(const bf16x8*)(src + 8);
            }
            __syncthreads();
            bf16x8 af[2], bfr[4];
#pragma unroll
            for (int mt = 0; mt < 2; ++mt)
                af[mt] = *(const bf16x8*)&Ws[wid * 32 + mt * 16 + fr][kg];
#pragma unroll
            for (int nt = 0; nt < 4; ++nt)
                bfr[nt] = cv ? *(const bf16x8*)&B4s[nt * 16 + fr][k0 + kg]
                             : *(const bf16x8*)&B1s[nt * 16 + fr][k0 + kg];
            if (cv == 0) {
#pragma unroll
                for (int mt = 0; mt < 2; ++mt)
#pragma unroll
                    for (int nt = 0; nt < 4; ++nt)
                        acc1[mt][nt] = __builtin_amdgcn_mfma_f32_16x16x32_bf16(af[mt], bfr[nt], acc1[mt][nt], 0, 0, 0);
            } else {
#pragma unroll
                for (int mt = 0; mt < 2; ++mt)
#pragma unroll
                    for (int nt = 0; nt < 4; ++nt)
                        acc4[mt][nt] = __builtin_amdgcn_mfma_f32_16x16x32_bf16(af[mt], bfr[nt], acc4[mt][nt], 0, 0, 0);
            }
            __syncthreads();
        }
    }

    const float pav = pa[0];
#pragma unroll
    for (int nt = 0; nt < 4; ++nt) {
        int nl = nt * 16 + fr;
#pragma unroll
        for (int mt = 0; mt < 2; ++mt) {
            int m = wid * 32 + mt * 16 + mrow;
#pragma unroll
            for (int r = 0; r < 4; ++r) {
                float v1 = acc1[mt][nt][r] + d1b[m + r];
                float v4 = acc4[mt][nt][r] + d4b[m + r];
                v1 = (v1 >= 0.f) ? v1 : pav * v1;
                v4 = (v4 >= 0.f) ? v4 : pav * v4;
                g_y1f[(size_t)(b * 128 + m + r) * kHW + hw0 + nl] = v1 + v4;
            }
        }
    }
}

// ---------------- 128x128 MFMA GEMM step (validated r5) ---------------------
template <int ACT>  // 0 tanh, 1 sigmoid
__device__ void gemm_step(const __bf16 (*__restrict__ Bsrc)[136],
                          const __bf16* __restrict__ Wg,
                          const float* __restrict__ bias,
                          __bf16 (*__restrict__ Tdst)[136],
                          float* __restrict__ gdst, int b, int hw0,
                          __bf16 (*__restrict__ Ws)[40])
{
    const int tid = threadIdx.x;
    const int lane = tid & 63, wid = tid >> 6;
    const int fr = lane & 15, kg = (lane >> 4) << 3, mrow = (lane >> 4) << 2;

    f32x4 acc[2][4];
#pragma unroll
    for (int mt = 0; mt < 2; ++mt)
#pragma unroll
        for (int nt = 0; nt < 4; ++nt)
#pragma unroll
            for (int r = 0; r < 4; ++r) acc[mt][nt][r] = 0.f;

#pragma unroll
    for (int k0 = 0; k0 < 128; k0 += 32) {
        {
            int m = tid >> 1, ks = (tid & 1) * 16;
            const __bf16* src = Wg + (size_t)m * 128 + k0 + ks;
            *(bf16x8*)&Ws[m][ks]     = *(const bf16x8*)src;
            *(bf16x8*)&Ws[m][ks + 8] = *(const bf16x8*)(src + 8);
        }
        __syncthreads();
        bf16x8 af[2], bfr[4];
#pragma unroll
        for (int mt = 0; mt < 2; ++mt)
            af[mt] = *(const bf16x8*)&Ws[wid * 32 + mt * 16 + fr][kg];
#pragma unroll
        for (int nt = 0; nt < 4; ++nt)
            bfr[nt] = *(const bf16x8*)&Bsrc[nt * 16 + fr][k0 + kg];
#pragma unroll
        for (int mt = 0; mt < 2; ++mt)
#pragma unroll
            for (int nt = 0; nt < 4; ++nt)
                acc[mt][nt] = __builtin_amdgcn_mfma_f32_16x16x32_bf16(af[mt], bfr[nt], acc[mt][nt], 0, 0, 0);
        __syncthreads();
    }

#pragma unroll
    for (int nt = 0; nt < 4; ++nt) {
        int nl = nt * 16 + fr;
#pragma unroll
        for (int mt = 0; mt < 2; ++mt) {
            int m = wid * 32 + mt * 16 + mrow;
            float vv[4];
#pragma unroll
            for (int r = 0; r < 4; ++r) {
                float v = acc[mt][nt][r] + bias[m + r];
                vv[r] = (ACT == 0) ? tanhf(v) : 1.f / (1.f + expf(-v));
            }
            if (Tdst) {
                bf16x4 o;
#pragma unroll
                for (int r = 0; r < 4; ++r) o[r] = (__bf16)vv[r];
                *(bf16x4*)&Tdst[nl][m] = o;
            } else {
#pragma unroll
                for (int r = 0; r < 4; ++r)
                    gdst[(size_t)(b * 128 + m + r) * kHW + hw0 + nl] = vv[r];
            }
        }
    }
}

// ---------------- MHSA pre-scan: y1 -> Z, F (validated r5) ------------------
__global__ __launch_bounds__(256) void k_prescan(
    const float* __restrict__ f1b1, const float* __restrict__ f1b2,
    const float* __restrict__ f2b1, const float* __restrict__ f2b2)
{
    __shared__ __bf16 Bt[64][136];
    __shared__ __bf16 Tt[64][136];
    __shared__ __bf16 Ws[128][40];    // total 45056 B

    const int tid = threadIdx.x;
    const int n0 = blockIdx.x * 64;
    const int b = n0 >> 14, hw0 = n0 & 16383;
    const int nl = tid & 63, wq = tid >> 6;

    for (int cc = 0; cc < 32; ++cc) {
        int c = wq * 32 + cc;
        Bt[nl][c] = (__bf16)g_y1f[(size_t)(b * 128 + c) * kHW + hw0 + nl];
    }
    __syncthreads();

    gemm_step<0>(Bt, g_w,         f1b1, Tt, nullptr, b, hw0, Ws);
    __syncthreads();
    gemm_step<0>(Tt, g_w + 16384, f1b2, nullptr, g_Zf, b, hw0, Ws);
    __syncthreads();
    gemm_step<0>(Bt, g_w + 32768, f2b1, Tt, nullptr, b, hw0, Ws);
    __syncthreads();
    gemm_step<1>(Tt, g_w + 49152, f2b2, nullptr, g_Ff, b, hw0, Ws);
}

// ---------------- SRU scan over H (validated r4) ----------------------------
__global__ __launch_bounds__(256) void k_scan()
{
    int b = blockIdx.x >> 6;
    int c = ((blockIdx.x & 63) << 1) + (threadIdx.x >> 7);
    int w = threadIdx.x & 127;
    size_t base = (size_t)(b * 128 + c) * kHW + w;
    float st = 0.f;
    if (c < 64) {
        for (int h = 127; h >= 0; --h) {
            size_t i = base + h * 128;
            float z = g_Zf[i], f = g_Ff[i];
            st = f * st + (1.f - f) * z;
            g_Zf[i] = 1.f / (1.f + expf(-st));
        }
    } else {
        for (int h = 0; h < 128; ++h) {
            size_t i = base + h * 128;
            float z = g_Zf[i], f = g_Ff[i];
            st = f * st + (1.f - f) * z;
            g_Zf[i] = 1.f / (1.f + expf(-st));
        }
    }
}

// ---------------- mega: pmul GEMM -> q GEMM (split-M) -> final GEMM ---------
__global__ __launch_bounds__(256) void k_mega(
    const float* __restrict__ pb3, const float* __restrict__ pb1,
    const float* __restrict__ pb2, float* __restrict__ out)
{
    __shared__ __bf16 Bt[64][136];            // 17408 B (y1 tile)
    __shared__ __align__(16) char U[33792];   // Pt[64][136] / Qt[64][264]
    __shared__ __bf16 Ws[128][40];            // 10240 B -> total 61440 B
    auto Pt = (__bf16 (*)[136])U;
    auto Qt = (__bf16 (*)[264])U;

    const int tid = threadIdx.x;
    const int n0 = blockIdx.x * 64;
    const int b = n0 >> 14, hw0 = n0 & 16383;
    const int lane = tid & 63, wid = tid >> 6;
    const int fr = lane & 15, kg = (lane >> 4) << 3, mrow = (lane >> 4) << 2;
    const int nl = tid & 63, wq = tid >> 6;

    for (int cc = 0; cc < 32; ++cc) {
        int c = wq * 32 + cc;
        Bt[nl][c] = (__bf16)g_y1f[(size_t)(b * 128 + c) * kHW + hw0 + nl];
    }
    __syncthreads();

    // ---- gemm0: p = (W3.y1 + pb3)*y1 + y1 -> Pt ----
    {
        f32x4 acc[2][4];
#pragma unroll
        for (int mt = 0; mt < 2; ++mt)
#pragma unroll
            for (int nt = 0; nt < 4; ++nt)
#pragma unroll
                for (int r = 0; r < 4; ++r) acc[mt][nt][r] = 0.f;
#pragma unroll
        for (int k0 = 0; k0 < 128; k0 += 32) {
            {
                int m = tid >> 1, ks = (tid & 1) * 16;
                const __bf16* src = g_w + 155648 + (size_t)m * 128 + k0 + ks;
                *(bf16x8*)&Ws[m][ks]     = *(const bf16x8*)src;
                *(bf16x8*)&Ws[m][ks + 8] = *(const bf16x8*)(src + 8);
            }
            __syncthreads();
            bf16x8 af[2], bfr[4];
#pragma unroll
            for (int mt = 0; mt < 2; ++mt)
                af[mt] = *(const bf16x8*)&Ws[wid * 32 + mt * 16 + fr][kg];
#pragma unroll
            for (int nt = 0; nt < 4; ++nt)
                bfr[nt] = *(const bf16x8*)&Bt[nt * 16 + fr][k0 + kg];
#pragma unroll
            for (int mt = 0; mt < 2; ++mt)
#pragma unroll
                for (int nt = 0; nt < 4; ++nt)
                    acc[mt][nt] = __builtin_amdgcn_mfma_f32_16x16x32_bf16(af[mt], bfr[nt], acc[mt][nt], 0, 0, 0);
            __syncthreads();
        }
#pragma unroll
        for (int nt = 0; nt < 4; ++nt) {
            int nlq = nt * 16 + fr;
#pragma unroll
            for (int mt = 0; mt < 2; ++mt) {
                int m = wid * 32 + mt * 16 + mrow;
                bf16x4 yv = *(const bf16x4*)&Bt[nlq][m];
                bf16x4 o;
#pragma unroll
                for (int r = 0; r < 4; ++r) {
                    float y = (float)yv[r];
                    float v = acc[mt][nt][r] + pb3[m + r];
                    o[r] = (__bf16)(v * y + y);
                }
                *(bf16x4*)&Pt[nlq][m] = o;
            }
        }
    }
    __syncthreads();

    // ---- gemm2: q = gelu(W1[256][128].p + pb1) -> Qt (aliases Pt; M split) --
    {
        f32x4 acc[2][2][4];   // [mh][mt][nt]
#pragma unroll
        for (int mh = 0; mh < 2; ++mh)
#pragma unroll
            for (int mt = 0; mt < 2; ++mt)
#pragma unroll
                for (int nt = 0; nt < 4; ++nt)
#pragma unroll
                    for (int r = 0; r < 4; ++r) acc[mh][mt][nt][r] = 0.f;
#pragma unroll
        for (int mh = 0; mh < 2; ++mh) {
#pragma unroll
            for (int k0 = 0; k0 < 128; k0 += 32) {
                {
                    int m = tid >> 1, ks = (tid & 1) * 16;
                    const __bf16* src = g_w + 65536 + (size_t)(mh * 128 + m) * 128 + k0 + ks;
                    *(bf16x8*)&Ws[m][ks]     = *(const bf16x8*)src;
                    *(bf16x8*)&Ws[m][ks + 8] = *(const bf16x8*)(src + 8);
                }
                __syncthreads();
                bf16x8 af[2], bfr[4];
#pragma unroll
                for (int mt = 0; mt < 2; ++mt)
                    af[mt] = *(const bf16x8*)&Ws[wid * 32 + mt * 16 + fr][kg];
#pragma unroll
                for (int nt = 0; nt < 4; ++nt)
                    bfr[nt] = *(const bf16x8*)&Pt[nt * 16 + fr][k0 + kg];
#pragma unroll
                for (int mt = 0; mt < 2; ++mt)
#pragma unroll
                    for (int nt = 0; nt < 4; ++nt)
                        acc[mh][mt][nt] = __builtin_amdgcn_mfma_f32_16x16x32_bf16(af[mt], bfr[nt], acc[mh][mt][nt], 0, 0, 0);
                __syncthreads();
            }
        }
        // Pt dead -> overwrite as Qt
#pragma unroll
        for (int mh = 0; mh < 2; ++mh)
#pragma unroll
            for (int nt = 0; nt < 4; ++nt) {
                int nlq = nt * 16 + fr;
#pragma unroll
                for (int mt = 0; mt < 2; ++mt) {
                    int m = mh * 128 + wid * 32 + mt * 16 + mrow;
                    bf16x4 o;
#pragma unroll
                    for (int r = 0; r < 4; ++r) {
                        float xx = acc[mh][mt][nt][r] + pb1[m + r];
                        o[r] = (__bf16)(0.5f * xx * (1.f + erff(xx * 0.70710678118f)));
                    }
                    *(bf16x4*)&Qt[nlq][m] = o;
                }
            }
    }
    __syncthreads();

    // ---- gemm3: out = W2[128][256].q + pb2 + y1*sig  (NCHW f32) ----
    {
        f32x4 acc[2][4];
#pragma unroll
        for (int mt = 0; mt < 2; ++mt)
#pragma unroll
            for (int nt = 0; nt < 4; ++nt)
#pragma unroll
                for (int r = 0; r < 4; ++r) acc[mt][nt][r] = 0.f;
#pragma unroll
        for (int k0 = 0; k0 < 256; k0 += 32) {
            {
                int m = tid >> 1, ks = (tid & 1) * 16;
                const __bf16* src = g_w + 98304 + (size_t)m * 256 + k0 + ks;
                *(bf16x8*)&Ws[m][ks]     = *(const bf16x8*)src;
                *(bf16x8*)&Ws[m][ks + 8] = *(const bf16x8*)(src + 8);
            }
            __syncthreads();
            bf16x8 af[2], bfr[4];
#pragma unroll
            for (int mt = 0; mt < 2; ++mt)
                af[mt] = *(const bf16x8*)&Ws[wid * 32 + mt * 16 + fr][kg];
#pragma unroll
            for (int nt = 0; nt < 4; ++nt)
                bfr[nt] = *(const bf16x8*)&Qt[nt * 16 + fr][k0 + kg];
#pragma unroll
            for (int mt = 0; mt < 2; ++mt)
#pragma unroll
                for (int nt = 0; nt < 4; ++nt)
                    acc[mt][nt] = __builtin_amdgcn_mfma_f32_16x16x32_bf16(af[mt], bfr[nt], acc[mt][nt], 0, 0, 0);
            __syncthreads();
        }
#pragma unroll
        for (int nt = 0; nt < 4; ++nt) {
            int hw = hw0 + nt * 16 + fr;
#pragma unroll
            for (int mt = 0; mt < 2; ++mt) {
                int m = wid * 32 + mt * 16 + mrow;
#pragma unroll
                for (int r = 0; r < 4; ++r) {
                    size_t i = (size_t)(b * 128 + m + r) * kHW + hw;
                    out[i] = acc[mt][nt][r] + pb2[m + r] + g_y1f[i] * g_Zf[i];
                }
            }
        }
    }
}

// ---------------- diagnostics ----------------------------------------------
__device__ __forceinline__ bool badf(float v) { return !(fabsf(v) <= 1e30f); }

__global__ __launch_bounds__(256) void k_diag(const float* __restrict__ out)
{
    size_t i = (size_t)blockIdx.x * 256 + threadIdx.x;  // 8388608
    unsigned f = 0;
    if (badf(g_y1f[i])) f |= 1u;
    if (badf(g_Zf[i]))  f |= 4u;
    if (badf(g_Ff[i]))  f |= 8u;
    if (badf(out[i]))   f |= 32u;
    if (f) atomicOr(&g_flag[0], f);
}

__global__ __launch_bounds__(256) void k_fix(float* __restrict__ out)
{
    unsigned fl = g_flag[0];
    if (!(fl & 32u)) return;
    size_t i = (size_t)blockIdx.x * 256 + threadIdx.x;
    out[i] = 20000.f + 100.f * (float)fl;
}

// ---------------------------------------------------------------------------
extern "C" void kernel_launch(void* const* d_in, const int* in_sizes, int n_in,
                              void* d_out, int out_size, void* d_ws, size_t ws_size,
                              hipStream_t stream)
{
    const float* x    = (const float*)d_in[0];
    const float* d1w  = (const float*)d_in[1];
    const float* d1b  = (const float*)d_in[2];
    const float* d4w  = (const float*)d_in[3];
    const float* d4b  = (const float*)d_in[4];
    const float* pa   = (const float*)d_in[5];
    const float* f1w1 = (const float*)d_in[6];
    const float* f1b1 = (const float*)d_in[7];
    const float* f1w2 = (const float*)d_in[8];
    const float* f1b2 = (const float*)d_in[9];
    const float* f2w1 = (const float*)d_in[10];
    const float* f2b1 = (const float*)d_in[11];
    const float* f2w2 = (const float*)d_in[12];
    const float* f2b2 = (const float*)d_in[13];
    const float* pw1  = (const float*)d_in[14];
    const float* pb1  = (const float*)d_in[15];
    const float* pw2  = (const float*)d_in[16];
    const float* pb2  = (const float*)d_in[17];
    const float* pw3  = (const float*)d_in[18];
    const float* pb3  = (const float*)d_in[19];
    float* out = (float*)d_out;

    k_zero<<<1, 1, 0, stream>>>();
    k_prepw<<<672, 256, 0, stream>>>(f1w1, f1w2, f2w1, f2w2, pw1, pw2, d1w, d4w, pw3);
    k_conv<<<1024, 256, 0, stream>>>(x, d1b, d4b, pa);
    k_prescan<<<1024, 256, 0, stream>>>(f1b1, f1b2, f2b1, f2b2);
    k_scan<<<256, 256, 0, stream>>>();
    k_mega<<<1024, 256, 0, stream>>>(pb3, pb1, pb2, out);
    k_diag<<<32768, 256, 0, stream>>>(out);
    k_fix<<<32768, 256, 0, stream>>>(out);

    (void)in_sizes; (void)n_in; (void)d_ws; (void)ws_size; (void)out_size;
}

// Round 7
// 146.886 us; speedup vs baseline: 13.0678x; 1.8565x over previous
//
#include <hip/hip_runtime.h>

// MSSFM round 7 — occupancy + traffic.
//   k_prepw: pack weights (bf16) incl. zero-padded im2col A1/A4.
//   k_fused: DPB conv (patch-direct im2col MFMA) -> y1 tile kept in LDS ->
//            4 chained GEMMs -> Z,F.   LDS 51.5KB (3 blocks/CU).
//   k_scan:  SRU over H, bf16 NHWC, sigmoid in place into g_Z.
//   k_mega:  pmul GEMM -> q GEMM (split-M) -> final GEMM.
//            LDS 45.1KB via Qt aliasing Bt+Pt (3 blocks/CU).
// All activations NHWC bf16: g_y1/g_Z/g_F [pixel=b*16384+h*128+w][c].
// HARD RULE: static LDS <= 64KB per kernel (r1-3 NaNs were silent launch
// failures from >64KB).

typedef __bf16 bf16x8 __attribute__((ext_vector_type(8)));
typedef __bf16 bf16x4 __attribute__((ext_vector_type(4)));
typedef float  f32x4  __attribute__((ext_vector_type(4)));

constexpr int kHW = 16384;   // 128*128

__device__ __align__(16) __bf16 g_y1[8388608];   // NHWC bf16
__device__ __align__(16) __bf16 g_Z [8388608];   // Z, then sigmoid(y2)
__device__ __align__(16) __bf16 g_F [8388608];   // F
// g_w: f1w1@0 f1w2@16384 f2w1@32768 f2w2@49152 pw1@65536 pw2@98304
//      A1@131072[128][96] A4@143360[128][96] pw3@155648
__device__ __align__(16) __bf16 g_w [172032];

// ---------------- pack weights to bf16 --------------------------------------
__global__ __launch_bounds__(256) void k_prepw(
    const float* __restrict__ f1w1, const float* __restrict__ f1w2,
    const float* __restrict__ f2w1, const float* __restrict__ f2w2,
    const float* __restrict__ pw1, const float* __restrict__ pw2,
    const float* __restrict__ d1w, const float* __restrict__ d4w,
    const float* __restrict__ pw3)
{
    int idx = blockIdx.x * 256 + threadIdx.x;  // 172032
    float v;
    if (idx < 16384)        v = f1w1[idx];
    else if (idx < 32768)   v = f1w2[idx - 16384];
    else if (idx < 49152)   v = f2w1[idx - 32768];
    else if (idx < 65536)   v = f2w2[idx - 49152];
    else if (idx < 98304)   v = pw1[idx - 65536];
    else if (idx < 131072)  v = pw2[idx - 98304];
    else if (idx < 155648) {
        // A1/A4: [128 c][96 k], k = tap*8+s (tap=kh*3+kw), taps 9..11 zero
        int r = idx - 131072;
        const float* src = d1w;
        if (r >= 12288) { r -= 12288; src = d4w; }
        int c = r / 96, k = r - c * 96;
        int tap = k >> 3, s = k & 7;
        v = (tap < 9) ? src[c * 72 + s * 9 + tap] : 0.f;
    } else                  v = pw3[idx - 155648];
    g_w[idx] = (__bf16)v;
}

// ---------------- 128x128 MFMA GEMM step (validated r5/r6) ------------------
// ACT: 0 tanh, 1 sigmoid. Output to LDS (Tdst) or NHWC bf16 global (gdst).
template <int ACT>
__device__ void gemm_step(const __bf16 (*__restrict__ Bsrc)[136],
                          const __bf16* __restrict__ Wg,
                          const float* __restrict__ bias,
                          __bf16 (*__restrict__ Tdst)[136],
                          __bf16* __restrict__ gdst, int n0,
                          __bf16 (*__restrict__ Ws)[40])
{
    const int tid = threadIdx.x;
    const int lane = tid & 63, wid = tid >> 6;
    const int fr = lane & 15, kg = (lane >> 4) << 3, mrow = (lane >> 4) << 2;

    f32x4 acc[2][4];
#pragma unroll
    for (int mt = 0; mt < 2; ++mt)
#pragma unroll
        for (int nt = 0; nt < 4; ++nt)
#pragma unroll
            for (int r = 0; r < 4; ++r) acc[mt][nt][r] = 0.f;

#pragma unroll
    for (int k0 = 0; k0 < 128; k0 += 32) {
        {
            int m = tid >> 1, ks = (tid & 1) * 16;
            const __bf16* src = Wg + (size_t)m * 128 + k0 + ks;
            *(bf16x8*)&Ws[m][ks]     = *(const bf16x8*)src;
            *(bf16x8*)&Ws[m][ks + 8] = *(const bf16x8*)(src + 8);
        }
        __syncthreads();
        bf16x8 af[2], bfr[4];
#pragma unroll
        for (int mt = 0; mt < 2; ++mt)
            af[mt] = *(const bf16x8*)&Ws[wid * 32 + mt * 16 + fr][kg];
#pragma unroll
        for (int nt = 0; nt < 4; ++nt)
            bfr[nt] = *(const bf16x8*)&Bsrc[nt * 16 + fr][k0 + kg];
#pragma unroll
        for (int mt = 0; mt < 2; ++mt)
#pragma unroll
            for (int nt = 0; nt < 4; ++nt)
                acc[mt][nt] = __builtin_amdgcn_mfma_f32_16x16x32_bf16(af[mt], bfr[nt], acc[mt][nt], 0, 0, 0);
        __syncthreads();
    }

#pragma unroll
    for (int nt = 0; nt < 4; ++nt) {
        int nl = nt * 16 + fr;
#pragma unroll
        for (int mt = 0; mt < 2; ++mt) {
            int m = wid * 32 + mt * 16 + mrow;
            bf16x4 o;
#pragma unroll
            for (int r = 0; r < 4; ++r) {
                float v = acc[mt][nt][r] + bias[m + r];
                o[r] = (__bf16)((ACT == 0) ? tanhf(v) : 1.f / (1.f + expf(-v)));
            }
            if (Tdst) *(bf16x4*)&Tdst[nl][m] = o;
            else      *(bf16x4*)&gdst[(size_t)(n0 + nl) * 128 + m] = o;
        }
    }
}

// ---------------- fused: DPB conv (im2col MFMA) + prescan (y1->Z,F) ---------
__global__ __launch_bounds__(256) void k_fused(
    const float* __restrict__ x, const float* __restrict__ d1b,
    const float* __restrict__ d4b, const float* __restrict__ pa,
    const float* __restrict__ f1b1, const float* __restrict__ f1b2,
    const float* __restrict__ f2b1, const float* __restrict__ f2b2)
{
    __shared__ __bf16 patch[5][80][8];   //  6400 B
    __shared__ __bf16 Bt[64][136];       // 17408 B (y1 tile)
    __shared__ __bf16 Tt[64][136];       // 17408 B
    __shared__ __bf16 Ws[128][40];       // 10240 B  -> 51456 B total

    const int tid = threadIdx.x;
    const int n0 = blockIdx.x * 64;            // global pixel base
    const int b = n0 >> 14, hw0 = n0 & 16383;
    const int h = hw0 >> 7, w0 = hw0 & 127;    // 64-pixel row segment

    // ---- stage x patch: rows {h-7,h-1,h,h+1,h+7} x cols [w0-7, w0+70] ------
    const int roff[5] = {-7, -1, 0, 1, 7};
    for (int t = tid; t < 400; t += 256) {
        int rs = t / 80, c = t - rs * 80;
        int row = h + roff[rs], wc = w0 + c - 7;
        bf16x8 v;
#pragma unroll
        for (int s = 0; s < 8; ++s) v[s] = (__bf16)0.f;
        if ((unsigned)row < 128u && (unsigned)wc < 128u && c < 78) {
#pragma unroll
            for (int s = 0; s < 8; ++s)
                v[s] = (__bf16)x[(size_t)(b * 8 + s) * kHW + row * 128 + wc];
        }
        *(bf16x8*)&patch[rs][c][0] = v;
    }

    const int lane = tid & 63, wid = tid >> 6;
    const int fr = lane & 15, kg = (lane >> 4) << 3, mrow = (lane >> 4) << 2;

    f32x4 acc1[2][4], acc4[2][4];
#pragma unroll
    for (int mt = 0; mt < 2; ++mt)
#pragma unroll
        for (int nt = 0; nt < 4; ++nt)
#pragma unroll
            for (int r = 0; r < 4; ++r) { acc1[mt][nt][r] = 0.f; acc4[mt][nt][r] = 0.f; }

#pragma unroll
    for (int cv = 0; cv < 2; ++cv) {
        const __bf16* Ag = g_w + (cv ? 143360 : 131072);
#pragma unroll
        for (int k0 = 0; k0 < 96; k0 += 32) {
            {
                int m = tid >> 1, ks = (tid & 1) * 16;
                const __bf16* src = Ag + (size_t)m * 96 + k0 + ks;
                *(bf16x8*)&Ws[m][ks]     = *(const bf16x8*)src;
                *(bf16x8*)&Ws[m][ks + 8] = *(const bf16x8*)(src + 8);
            }
            __syncthreads();
            bf16x8 af[2], bfr[4];
#pragma unroll
            for (int mt = 0; mt < 2; ++mt)
                af[mt] = *(const bf16x8*)&Ws[wid * 32 + mt * 16 + fr][kg];
            int tap = (k0 + kg) >> 3;   // uniform within a 16-lane group
#pragma unroll
            for (int nt = 0; nt < 4; ++nt) {
                bf16x8 bv;
#pragma unroll
                for (int i = 0; i < 8; ++i) bv[i] = (__bf16)0.f;
                if (tap < 9) {
                    int dh = tap / 3 - 1, dw = tap % 3 - 1;
                    int rowsel = cv ? (dh + 1) * 2 : dh + 2;
                    int col = nt * 16 + fr + dw * (cv ? 7 : 1) + 7;
                    bv = *(const bf16x8*)&patch[rowsel][col][0];
                }
                bfr[nt] = bv;
            }
            if (cv == 0) {
#pragma unroll
                for (int mt = 0; mt < 2; ++mt)
#pragma unroll
                    for (int nt = 0; nt < 4; ++nt)
                        acc1[mt][nt] = __builtin_amdgcn_mfma_f32_16x16x32_bf16(af[mt], bfr[nt], acc1[mt][nt], 0, 0, 0);
            } else {
#pragma unroll
                for (int mt = 0; mt < 2; ++mt)
#pragma unroll
                    for (int nt = 0; nt < 4; ++nt)
                        acc4[mt][nt] = __builtin_amdgcn_mfma_f32_16x16x32_bf16(af[mt], bfr[nt], acc4[mt][nt], 0, 0, 0);
            }
            __syncthreads();
        }
    }

    // ---- epilogue: y1 = prelu + prelu -> Bt (LDS) + g_y1 (NHWC) ----
    const float pav = pa[0];
#pragma unroll
    for (int nt = 0; nt < 4; ++nt) {
        int nl = nt * 16 + fr;
#pragma unroll
        for (int mt = 0; mt < 2; ++mt) {
            int m = wid * 32 + mt * 16 + mrow;
            bf16x4 o;
#pragma unroll
            for (int r = 0; r < 4; ++r) {
                float v1 = acc1[mt][nt][r] + d1b[m + r];
                float v4 = acc4[mt][nt][r] + d4b[m + r];
                v1 = (v1 >= 0.f) ? v1 : pav * v1;
                v4 = (v4 >= 0.f) ? v4 : pav * v4;
                o[r] = (__bf16)(v1 + v4);
            }
            *(bf16x4*)&Bt[nl][m] = o;
            *(bf16x4*)&g_y1[(size_t)(n0 + nl) * 128 + m] = o;
        }
    }
    __syncthreads();

    // ---- prescan: Z = tanh(conv(tanh(conv))), F = sigmoid(...) ----
    gemm_step<0>(Bt, g_w,         f1b1, Tt, nullptr, n0, Ws);
    __syncthreads();
    gemm_step<0>(Tt, g_w + 16384, f1b2, nullptr, g_Z, n0, Ws);
    __syncthreads();
    gemm_step<0>(Bt, g_w + 32768, f2b1, Tt, nullptr, n0, Ws);
    __syncthreads();
    gemm_step<1>(Tt, g_w + 49152, f2b2, nullptr, g_F, n0, Ws);
}

// ---------------- SRU scan over H (bf16 NHWC); sigmoid in place -------------
__global__ __launch_bounds__(256) void k_scan()
{
    int b = blockIdx.x >> 6;
    int w = ((blockIdx.x & 63) << 1) + (threadIdx.x >> 7);
    int c = threadIdx.x & 127;
    size_t base = ((size_t)(b * kHW + w)) * 128 + c;   // element at h=0
    float st = 0.f;
    if (c < 64) {  // reverse scan: y2[h] = f[h]*y2[h+1] + (1-f[h])*z[h]
#pragma unroll 8
        for (int h = 127; h >= 0; --h) {
            size_t i = base + (size_t)h * 16384;
            float z = (float)g_Z[i], f = (float)g_F[i];
            st = f * st + (1.f - f) * z;
            g_Z[i] = (__bf16)(1.f / (1.f + expf(-st)));
        }
    } else {       // forward scan (flip(reverse(flip)) algebra)
#pragma unroll 8
        for (int h = 0; h < 128; ++h) {
            size_t i = base + (size_t)h * 16384;
            float z = (float)g_Z[i], f = (float)g_F[i];
            st = f * st + (1.f - f) * z;
            g_Z[i] = (__bf16)(1.f / (1.f + expf(-st)));
        }
    }
}

// ---------------- mega: pmul GEMM -> q GEMM (split-M) -> final GEMM ---------
__global__ __launch_bounds__(256) void k_mega(
    const float* __restrict__ pb3, const float* __restrict__ pb1,
    const float* __restrict__ pb2, float* __restrict__ out)
{
    __shared__ __align__(16) char U[34816];   // Bt[64][136] | Pt[64][136] ; Qt aliases both
    __shared__ __bf16 Ws[128][40];            // 10240 -> total 45056 B
    auto Bt = (__bf16 (*)[136])U;
    auto Pt = (__bf16 (*)[136])(U + 17408);
    auto Qt = (__bf16 (*)[264])U;

    const int tid = threadIdx.x;
    const int n0 = blockIdx.x * 64;
    const int b = n0 >> 14, hw0 = n0 & 16383;
    const int lane = tid & 63, wid = tid >> 6;
    const int fr = lane & 15, kg = (lane >> 4) << 3, mrow = (lane >> 4) << 2;

    // stage y1 tile (NHWC bf16, coalesced)
    {
        int n = tid >> 2, ks = (tid & 3) * 32;
        const __bf16* src = g_y1 + (size_t)(n0 + n) * 128 + ks;
        *(bf16x8*)&Bt[n][ks]      = *(const bf16x8*)src;
        *(bf16x8*)&Bt[n][ks + 8]  = *(const bf16x8*)(src + 8);
        *(bf16x8*)&Bt[n][ks + 16] = *(const bf16x8*)(src + 16);
        *(bf16x8*)&Bt[n][ks + 24] = *(const bf16x8*)(src + 24);
    }
    __syncthreads();

    // ---- gemm0: p = (W3.y1 + pb3)*y1 + y1 -> Pt ----
    {
        f32x4 acc[2][4];
#pragma unroll
        for (int mt = 0; mt < 2; ++mt)
#pragma unroll
            for (int nt = 0; nt < 4; ++nt)
#pragma unroll
                for (int r = 0; r < 4; ++r) acc[mt][nt][r] = 0.f;
#pragma unroll
        for (int k0 = 0; k0 < 128; k0 += 32) {
            {
                int m = tid >> 1, ks = (tid & 1) * 16;
                const __bf16* src = g_w + 155648 + (size_t)m * 128 + k0 + ks;
                *(bf16x8*)&Ws[m][ks]     = *(const bf16x8*)src;
                *(bf16x8*)&Ws[m][ks + 8] = *(const bf16x8*)(src + 8);
            }
            __syncthreads();
            bf16x8 af[2], bfr[4];
#pragma unroll
            for (int mt = 0; mt < 2; ++mt)
                af[mt] = *(const bf16x8*)&Ws[wid * 32 + mt * 16 + fr][kg];
#pragma unroll
            for (int nt = 0; nt < 4; ++nt)
                bfr[nt] = *(const bf16x8*)&Bt[nt * 16 + fr][k0 + kg];
#pragma unroll
            for (int mt = 0; mt < 2; ++mt)
#pragma unroll
                for (int nt = 0; nt < 4; ++nt)
                    acc[mt][nt] = __builtin_amdgcn_mfma_f32_16x16x32_bf16(af[mt], bfr[nt], acc[mt][nt], 0, 0, 0);
            __syncthreads();
        }
#pragma unroll
        for (int nt = 0; nt < 4; ++nt) {
            int nl = nt * 16 + fr;
#pragma unroll
            for (int mt = 0; mt < 2; ++mt) {
                int m = wid * 32 + mt * 16 + mrow;
                bf16x4 yv = *(const bf16x4*)&Bt[nl][m];
                bf16x4 o;
#pragma unroll
                for (int r = 0; r < 4; ++r) {
                    float y = (float)yv[r];
                    o[r] = (__bf16)((acc[mt][nt][r] + pb3[m + r]) * y + y);
                }
                *(bf16x4*)&Pt[nl][m] = o;
            }
        }
    }
    __syncthreads();

    // ---- gemm2: q = gelu(W1[256][128].p + pb1) -> Qt (aliases Bt+Pt) ----
    {
        f32x4 acc[2][2][4];   // [mh][mt][nt]
#pragma unroll
        for (int mh = 0; mh < 2; ++mh)
#pragma unroll
            for (int mt = 0; mt < 2; ++mt)
#pragma unroll
                for (int nt = 0; nt < 4; ++nt)
#pragma unroll
                    for (int r = 0; r < 4; ++r) acc[mh][mt][nt][r] = 0.f;
#pragma unroll
        for (int mh = 0; mh < 2; ++mh) {
#pragma unroll
            for (int k0 = 0; k0 < 128; k0 += 32) {
                {
                    int m = tid >> 1, ks = (tid & 1) * 16;
                    const __bf16* src = g_w + 65536 + (size_t)(mh * 128 + m) * 128 + k0 + ks;
                    *(bf16x8*)&Ws[m][ks]     = *(const bf16x8*)src;
                    *(bf16x8*)&Ws[m][ks + 8] = *(const bf16x8*)(src + 8);
                }
                __syncthreads();
                bf16x8 af[2], bfr[4];
#pragma unroll
                for (int mt = 0; mt < 2; ++mt)
                    af[mt] = *(const bf16x8*)&Ws[wid * 32 + mt * 16 + fr][kg];
#pragma unroll
                for (int nt = 0; nt < 4; ++nt)
                    bfr[nt] = *(const bf16x8*)&Pt[nt * 16 + fr][k0 + kg];
#pragma unroll
                for (int mt = 0; mt < 2; ++mt)
#pragma unroll
                    for (int nt = 0; nt < 4; ++nt)
                        acc[mh][mt][nt] = __builtin_amdgcn_mfma_f32_16x16x32_bf16(af[mt], bfr[nt], acc[mh][mt][nt], 0, 0, 0);
                __syncthreads();
            }
        }
        // Bt & Pt dead -> write Qt over the union
#pragma unroll
        for (int mh = 0; mh < 2; ++mh)
#pragma unroll
            for (int nt = 0; nt < 4; ++nt) {
                int nl = nt * 16 + fr;
#pragma unroll
                for (int mt = 0; mt < 2; ++mt) {
                    int m = mh * 128 + wid * 32 + mt * 16 + mrow;
                    bf16x4 o;
#pragma unroll
                    for (int r = 0; r < 4; ++r) {
                        float xx = acc[mh][mt][nt][r] + pb1[m + r];
                        o[r] = (__bf16)(0.5f * xx * (1.f + erff(xx * 0.70710678118f)));
                    }
                    *(bf16x4*)&Qt[nl][m] = o;
                }
            }
    }
    __syncthreads();

    // ---- gemm3: out = W2[128][256].q + pb2 + y1*sig  (NCHW f32 store) ----
    {
        f32x4 acc[2][4];
#pragma unroll
        for (int mt = 0; mt < 2; ++mt)
#pragma unroll
            for (int nt = 0; nt < 4; ++nt)
#pragma unroll
                for (int r = 0; r < 4; ++r) acc[mt][nt][r] = 0.f;
#pragma unroll
        for (int k0 = 0; k0 < 256; k0 += 32) {
            {
                int m = tid >> 1, ks = (tid & 1) * 16;
                const __bf16* src = g_w + 98304 + (size_t)m * 256 + k0 + ks;
                *(bf16x8*)&Ws[m][ks]     = *(const bf16x8*)src;
                *(bf16x8*)&Ws[m][ks + 8] = *(const bf16x8*)(src + 8);
            }
            __syncthreads();
            bf16x8 af[2], bfr[4];
#pragma unroll
            for (int mt = 0; mt < 2; ++mt)
                af[mt] = *(const bf16x8*)&Ws[wid * 32 + mt * 16 + fr][kg];
#pragma unroll
            for (int nt = 0; nt < 4; ++nt)
                bfr[nt] = *(const bf16x8*)&Qt[nt * 16 + fr][k0 + kg];
#pragma unroll
            for (int mt = 0; mt < 2; ++mt)
#pragma unroll
                for (int nt = 0; nt < 4; ++nt)
                    acc[mt][nt] = __builtin_amdgcn_mfma_f32_16x16x32_bf16(af[mt], bfr[nt], acc[mt][nt], 0, 0, 0);
            __syncthreads();
        }
#pragma unroll
        for (int nt = 0; nt < 4; ++nt) {
            int hw = hw0 + nt * 16 + fr;
            size_t pbase = (size_t)(n0 + nt * 16 + fr) * 128;
#pragma unroll
            for (int mt = 0; mt < 2; ++mt) {
                int m = wid * 32 + mt * 16 + mrow;
                bf16x4 yv = *(const bf16x4*)&g_y1[pbase + m];
                bf16x4 sv = *(const bf16x4*)&g_Z[pbase + m];
#pragma unroll
                for (int r = 0; r < 4; ++r) {
                    out[(size_t)(b * 128 + m + r) * kHW + hw] =
                        acc[mt][nt][r] + pb2[m + r] + (float)yv[r] * (float)sv[r];
                }
            }
        }
    }
}

// ---------------------------------------------------------------------------
extern "C" void kernel_launch(void* const* d_in, const int* in_sizes, int n_in,
                              void* d_out, int out_size, void* d_ws, size_t ws_size,
                              hipStream_t stream)
{
    const float* x    = (const float*)d_in[0];
    const float* d1w  = (const float*)d_in[1];
    const float* d1b  = (const float*)d_in[2];
    const float* d4w  = (const float*)d_in[3];
    const float* d4b  = (const float*)d_in[4];
    const float* pa   = (const float*)d_in[5];
    const float* f1w1 = (const float*)d_in[6];
    const float* f1b1 = (const float*)d_in[7];
    const float* f1w2 = (const float*)d_in[8];
    const float* f1b2 = (const float*)d_in[9];
    const float* f2w1 = (const float*)d_in[10];
    const float* f2b1 = (const float*)d_in[11];
    const float* f2w2 = (const float*)d_in[12];
    const float* f2b2 = (const float*)d_in[13];
    const float* pw1  = (const float*)d_in[14];
    const float* pb1  = (const float*)d_in[15];
    const float* pw2  = (const float*)d_in[16];
    const float* pb2  = (const float*)d_in[17];
    const float* pw3  = (const float*)d_in[18];
    const float* pb3  = (const float*)d_in[19];
    float* out = (float*)d_out;

    k_prepw<<<672, 256, 0, stream>>>(f1w1, f1w2, f2w1, f2w2, pw1, pw2, d1w, d4w, pw3);
    k_fused<<<1024, 256, 0, stream>>>(x, d1b, d4b, pa, f1b1, f1b2, f2b1, f2b2);
    k_scan<<<256, 256, 0, stream>>>();
    k_mega<<<1024, 256, 0, stream>>>(pb3, pb1, pb2, out);

    (void)in_sizes; (void)n_in; (void)d_ws; (void)ws_size; (void)out_size;
}

// Round 10
// 137.735 us; speedup vs baseline: 13.9361x; 1.0664x over previous
//
#include <hip/hip_runtime.h>

// MSSFM round 10 — round-7 structure (compiled+passed, 146.9us) with ONE
// change: tanh/sigmoid via MANUAL exp2 (pure arithmetic: clamp + floor +
// deg-5 Taylor + exponent bit-assembly). r8 (__expf) and r9
// (__builtin_amdgcn_exp2f) both deterministically segfault ROCm 7.2 clang;
// libm tanhf/expf compile but cost ~30 VALU ops w/ branches (r7: k_fused
// VALUBusy 50%). This formulation uses only instruction classes already
// present elsewhere in this TU.
// HARD RULE: static LDS <= 64KB per kernel.

typedef __bf16 bf16x8 __attribute__((ext_vector_type(8)));
typedef __bf16 bf16x4 __attribute__((ext_vector_type(4)));
typedef float  f32x4  __attribute__((ext_vector_type(4)));

constexpr int kHW = 16384;   // 128*128

__device__ __align__(16) __bf16 g_y1[8388608];   // NHWC bf16
__device__ __align__(16) __bf16 g_Z [8388608];   // Z, then sigmoid(y2)
__device__ __align__(16) __bf16 g_F [8388608];   // F
// g_w: f1w1@0 f1w2@16384 f2w1@32768 f2w2@49152 pw1@65536 pw2@98304
//      A1@131072[128][96] A4@143360[128][96] pw3@155648
__device__ __align__(16) __bf16 g_w [172032];

// 2^x, pure arithmetic. Rel err ~1e-4 (<< bf16 eps 4e-3). Saturates safely.
__device__ __forceinline__ float fast_exp2(float x)
{
    x = fminf(fmaxf(x, -125.f), 125.f);
    float n = floorf(x);
    float f = x - n;   // [0,1)
    float p = 1.f + f * (0.69314718f + f * (0.24022651f + f * (0.05550411f +
              f * (0.00961813f + f * 0.00133336f))));
    return __int_as_float(((int)n + 127) << 23) * p;
}
__device__ __forceinline__ float fast_tanh(float x)
{
    return 1.f - 2.f / (fast_exp2(2.88539008f * x) + 1.f);
}
__device__ __forceinline__ float fast_sig(float x)
{
    return 1.f / (1.f + fast_exp2(-1.44269504f * x));
}

// ---------------- pack weights to bf16 --------------------------------------
__global__ __launch_bounds__(256) void k_prepw(
    const float* __restrict__ f1w1, const float* __restrict__ f1w2,
    const float* __restrict__ f2w1, const float* __restrict__ f2w2,
    const float* __restrict__ pw1, const float* __restrict__ pw2,
    const float* __restrict__ d1w, const float* __restrict__ d4w,
    const float* __restrict__ pw3)
{
    int idx = blockIdx.x * 256 + threadIdx.x;  // 172032
    float v;
    if (idx < 16384)        v = f1w1[idx];
    else if (idx < 32768)   v = f1w2[idx - 16384];
    else if (idx < 49152)   v = f2w1[idx - 32768];
    else if (idx < 65536)   v = f2w2[idx - 49152];
    else if (idx < 98304)   v = pw1[idx - 65536];
    else if (idx < 131072)  v = pw2[idx - 98304];
    else if (idx < 155648) {
        // A1/A4: [128 c][96 k], k = tap*8+s (tap=kh*3+kw), taps 9..11 zero
        int r = idx - 131072;
        const float* src = d1w;
        if (r >= 12288) { r -= 12288; src = d4w; }
        int c = r / 96, k = r - c * 96;
        int tap = k >> 3, s = k & 7;
        v = (tap < 9) ? src[c * 72 + s * 9 + tap] : 0.f;
    } else                  v = pw3[idx - 155648];
    g_w[idx] = (__bf16)v;
}

// ---------------- 128x128 MFMA GEMM step (validated r5/r6/r7) ---------------
// ACT: 0 tanh, 1 sigmoid. Output to LDS (Tdst) or NHWC bf16 global (gdst).
template <int ACT>
__device__ void gemm_step(const __bf16 (*__restrict__ Bsrc)[136],
                          const __bf16* __restrict__ Wg,
                          const float* __restrict__ bias,
                          __bf16 (*__restrict__ Tdst)[136],
                          __bf16* __restrict__ gdst, int n0,
                          __bf16 (*__restrict__ Ws)[40])
{
    const int tid = threadIdx.x;
    const int lane = tid & 63, wid = tid >> 6;
    const int fr = lane & 15, kg = (lane >> 4) << 3, mrow = (lane >> 4) << 2;

    f32x4 acc[2][4];
#pragma unroll
    for (int mt = 0; mt < 2; ++mt)
#pragma unroll
        for (int nt = 0; nt < 4; ++nt)
#pragma unroll
            for (int r = 0; r < 4; ++r) acc[mt][nt][r] = 0.f;

#pragma unroll
    for (int k0 = 0; k0 < 128; k0 += 32) {
        {
            int m = tid >> 1, ks = (tid & 1) * 16;
            const __bf16* src = Wg + (size_t)m * 128 + k0 + ks;
            *(bf16x8*)&Ws[m][ks]     = *(const bf16x8*)src;
            *(bf16x8*)&Ws[m][ks + 8] = *(const bf16x8*)(src + 8);
        }
        __syncthreads();
        bf16x8 af[2], bfr[4];
#pragma unroll
        for (int mt = 0; mt < 2; ++mt)
            af[mt] = *(const bf16x8*)&Ws[wid * 32 + mt * 16 + fr][kg];
#pragma unroll
        for (int nt = 0; nt < 4; ++nt)
            bfr[nt] = *(const bf16x8*)&Bsrc[nt * 16 + fr][k0 + kg];
#pragma unroll
        for (int mt = 0; mt < 2; ++mt)
#pragma unroll
            for (int nt = 0; nt < 4; ++nt)
                acc[mt][nt] = __builtin_amdgcn_mfma_f32_16x16x32_bf16(af[mt], bfr[nt], acc[mt][nt], 0, 0, 0);
        __syncthreads();
    }

#pragma unroll
    for (int nt = 0; nt < 4; ++nt) {
        int nl = nt * 16 + fr;
#pragma unroll
        for (int mt = 0; mt < 2; ++mt) {
            int m = wid * 32 + mt * 16 + mrow;
            bf16x4 o;
#pragma unroll
            for (int r = 0; r < 4; ++r) {
                float v = acc[mt][nt][r] + bias[m + r];
                o[r] = (__bf16)((ACT == 0) ? fast_tanh(v) : fast_sig(v));
            }
            if (Tdst) *(bf16x4*)&Tdst[nl][m] = o;
            else      *(bf16x4*)&gdst[(size_t)(n0 + nl) * 128 + m] = o;
        }
    }
}

// ---------------- fused: DPB conv (im2col MFMA) + prescan (y1->Z,F) ---------
__global__ __launch_bounds__(256) void k_fused(
    const float* __restrict__ x, const float* __restrict__ d1b,
    const float* __restrict__ d4b, const float* __restrict__ pa,
    const float* __restrict__ f1b1, const float* __restrict__ f1b2,
    const float* __restrict__ f2b1, const float* __restrict__ f2b2)
{
    __shared__ __bf16 patch[5][80][8];   //  6400 B
    __shared__ __bf16 Bt[64][136];       // 17408 B (y1 tile)
    __shared__ __bf16 Tt[64][136];       // 17408 B
    __shared__ __bf16 Ws[128][40];       // 10240 B  -> 51456 B total

    const int tid = threadIdx.x;
    const int n0 = blockIdx.x * 64;            // global pixel base
    const int b = n0 >> 14, hw0 = n0 & 16383;
    const int h = hw0 >> 7, w0 = hw0 & 127;    // 64-pixel row segment

    // ---- stage x patch: rows {h-7,h-1,h,h+1,h+7} x cols [w0-7, w0+70] ------
    const int roff[5] = {-7, -1, 0, 1, 7};
    for (int t = tid; t < 400; t += 256) {
        int rs = t / 80, c = t - rs * 80;
        int row = h + roff[rs], wc = w0 + c - 7;
        bf16x8 v;
#pragma unroll
        for (int s = 0; s < 8; ++s) v[s] = (__bf16)0.f;
        if ((unsigned)row < 128u && (unsigned)wc < 128u && c < 78) {
#pragma unroll
            for (int s = 0; s < 8; ++s)
                v[s] = (__bf16)x[(size_t)(b * 8 + s) * kHW + row * 128 + wc];
        }
        *(bf16x8*)&patch[rs][c][0] = v;
    }

    const int lane = tid & 63, wid = tid >> 6;
    const int fr = lane & 15, kg = (lane >> 4) << 3, mrow = (lane >> 4) << 2;

    f32x4 acc1[2][4], acc4[2][4];
#pragma unroll
    for (int mt = 0; mt < 2; ++mt)
#pragma unroll
        for (int nt = 0; nt < 4; ++nt)
#pragma unroll
            for (int r = 0; r < 4; ++r) { acc1[mt][nt][r] = 0.f; acc4[mt][nt][r] = 0.f; }

#pragma unroll
    for (int cv = 0; cv < 2; ++cv) {
        const __bf16* Ag = g_w + (cv ? 143360 : 131072);
#pragma unroll
        for (int k0 = 0; k0 < 96; k0 += 32) {
            {
                int m = tid >> 1, ks = (tid & 1) * 16;
                const __bf16* src = Ag + (size_t)m * 96 + k0 + ks;
                *(bf16x8*)&Ws[m][ks]     = *(const bf16x8*)src;
                *(bf16x8*)&Ws[m][ks + 8] = *(const bf16x8*)(src + 8);
            }
            __syncthreads();
            bf16x8 af[2], bfr[4];
#pragma unroll
            for (int mt = 0; mt < 2; ++mt)
                af[mt] = *(const bf16x8*)&Ws[wid * 32 + mt * 16 + fr][kg];
            int tap = (k0 + kg) >> 3;   // uniform within a 16-lane group
#pragma unroll
            for (int nt = 0; nt < 4; ++nt) {
                bf16x8 bv;
#pragma unroll
                for (int i = 0; i < 8; ++i) bv[i] = (__bf16)0.f;
                if (tap < 9) {
                    int dh = tap / 3 - 1, dw = tap % 3 - 1;
                    int rowsel = cv ? (dh + 1) * 2 : dh + 2;
                    int col = nt * 16 + fr + dw * (cv ? 7 : 1) + 7;
                    bv = *(const bf16x8*)&patch[rowsel][col][0];
                }
                bfr[nt] = bv;
            }
            if (cv == 0) {
#pragma unroll
                for (int mt = 0; mt < 2; ++mt)
#pragma unroll
                    for (int nt = 0; nt < 4; ++nt)
                        acc1[mt][nt] = __builtin_amdgcn_mfma_f32_16x16x32_bf16(af[mt], bfr[nt], acc1[mt][nt], 0, 0, 0);
            } else {
#pragma unroll
                for (int mt = 0; mt < 2; ++mt)
#pragma unroll
                    for (int nt = 0; nt < 4; ++nt)
                        acc4[mt][nt] = __builtin_amdgcn_mfma_f32_16x16x32_bf16(af[mt], bfr[nt], acc4[mt][nt], 0, 0, 0);
            }
            __syncthreads();
        }
    }

    // ---- epilogue: y1 = prelu + prelu -> Bt (LDS) + g_y1 (NHWC) ----
    const float pav = pa[0];
#pragma unroll
    for (int nt = 0; nt < 4; ++nt) {
        int nl = nt * 16 + fr;
#pragma unroll
        for (int mt = 0; mt < 2; ++mt) {
            int m = wid * 32 + mt * 16 + mrow;
            bf16x4 o;
#pragma unroll
            for (int r = 0; r < 4; ++r) {
                float v1 = acc1[mt][nt][r] + d1b[m + r];
                float v4 = acc4[mt][nt][r] + d4b[m + r];
                v1 = (v1 >= 0.f) ? v1 : pav * v1;
                v4 = (v4 >= 0.f) ? v4 : pav * v4;
                o[r] = (__bf16)(v1 + v4);
            }
            *(bf16x4*)&Bt[nl][m] = o;
            *(bf16x4*)&g_y1[(size_t)(n0 + nl) * 128 + m] = o;
        }
    }
    __syncthreads();

    // ---- prescan: Z = tanh(conv(tanh(conv))), F = sigmoid(...) ----
    gemm_step<0>(Bt, g_w,         f1b1, Tt, nullptr, n0, Ws);
    __syncthreads();
    gemm_step<0>(Tt, g_w + 16384, f1b2, nullptr, g_Z, n0, Ws);
    __syncthreads();
    gemm_step<0>(Bt, g_w + 32768, f2b1, Tt, nullptr, n0, Ws);
    __syncthreads();
    gemm_step<1>(Tt, g_w + 49152, f2b2, nullptr, g_F, n0, Ws);
}

// ---------------- SRU scan over H (bf16 NHWC); sigmoid in place -------------
__global__ __launch_bounds__(256) void k_scan()
{
    int b = blockIdx.x >> 6;
    int w = ((blockIdx.x & 63) << 1) + (threadIdx.x >> 7);
    int c = threadIdx.x & 127;
    size_t base = ((size_t)(b * kHW + w)) * 128 + c;   // element at h=0
    float st = 0.f;
    if (c < 64) {  // reverse scan: y2[h] = f[h]*y2[h+1] + (1-f[h])*z[h]
#pragma unroll 8
        for (int h = 127; h >= 0; --h) {
            size_t i = base + (size_t)h * 16384;
            float z = (float)g_Z[i], f = (float)g_F[i];
            st = f * st + (1.f - f) * z;
            g_Z[i] = (__bf16)fast_sig(st);
        }
    } else {       // forward scan (flip(reverse(flip)) algebra)
#pragma unroll 8
        for (int h = 0; h < 128; ++h) {
            size_t i = base + (size_t)h * 16384;
            float z = (float)g_Z[i], f = (float)g_F[i];
            st = f * st + (1.f - f) * z;
            g_Z[i] = (__bf16)fast_sig(st);
        }
    }
}

// ---------------- mega: pmul GEMM -> q GEMM (split-M) -> final GEMM ---------
__global__ __launch_bounds__(256) void k_mega(
    const float* __restrict__ pb3, const float* __restrict__ pb1,
    const float* __restrict__ pb2, float* __restrict__ out)
{
    __shared__ __align__(16) char U[34816];   // Bt[64][136] | Pt[64][136] ; Qt aliases both
    __shared__ __bf16 Ws[128][40];            // 10240 -> total 45056 B
    auto Bt = (__bf16 (*)[136])U;
    auto Pt = (__bf16 (*)[136])(U + 17408);
    auto Qt = (__bf16 (*)[264])U;

    const int tid = threadIdx.x;
    const int n0 = blockIdx.x * 64;
    const int b = n0 >> 14, hw0 = n0 & 16383;
    const int lane = tid & 63, wid = tid >> 6;
    const int fr = lane & 15, kg = (lane >> 4) << 3, mrow = (lane >> 4) << 2;

    // stage y1 tile (NHWC bf16, coalesced)
    {
        int n = tid >> 2, ks = (tid & 3) * 32;
        const __bf16* src = g_y1 + (size_t)(n0 + n) * 128 + ks;
        *(bf16x8*)&Bt[n][ks]      = *(const bf16x8*)src;
        *(bf16x8*)&Bt[n][ks + 8]  = *(const bf16x8*)(src + 8);
        *(bf16x8*)&Bt[n][ks + 16] = *(const bf16x8*)(src + 16);
        *(bf16x8*)&Bt[n][ks + 24] = *(const bf16x8*)(src + 24);
    }
    __syncthreads();

    // ---- gemm0: p = (W3.y1 + pb3)*y1 + y1 -> Pt ----
    {
        f32x4 acc[2][4];
#pragma unroll
        for (int mt = 0; mt < 2; ++mt)
#pragma unroll
            for (int nt = 0; nt < 4; ++nt)
#pragma unroll
                for (int r = 0; r < 4; ++r) acc[mt][nt][r] = 0.f;
#pragma unroll
        for (int k0 = 0; k0 < 128; k0 += 32) {
            {
                int m = tid >> 1, ks = (tid & 1) * 16;
                const __bf16* src = g_w + 155648 + (size_t)m * 128 + k0 + ks;
                *(bf16x8*)&Ws[m][ks]     = *(const bf16x8*)src;
                *(bf16x8*)&Ws[m][ks + 8] = *(const bf16x8*)(src + 8);
            }
            __syncthreads();
            bf16x8 af[2], bfr[4];
#pragma unroll
            for (int mt = 0; mt < 2; ++mt)
                af[mt] = *(const bf16x8*)&Ws[wid * 32 + mt * 16 + fr][kg];
#pragma unroll
            for (int nt = 0; nt < 4; ++nt)
                bfr[nt] = *(const bf16x8*)&Bt[nt * 16 + fr][k0 + kg];
#pragma unroll
            for (int mt = 0; mt < 2; ++mt)
#pragma unroll
                for (int nt = 0; nt < 4; ++nt)
                    acc[mt][nt] = __builtin_amdgcn_mfma_f32_16x16x32_bf16(af[mt], bfr[nt], acc[mt][nt], 0, 0, 0);
            __syncthreads();
        }
#pragma unroll
        for (int nt = 0; nt < 4; ++nt) {
            int nl = nt * 16 + fr;
#pragma unroll
            for (int mt = 0; mt < 2; ++mt) {
                int m = wid * 32 + mt * 16 + mrow;
                bf16x4 yv = *(const bf16x4*)&Bt[nl][m];
                bf16x4 o;
#pragma unroll
                for (int r = 0; r < 4; ++r) {
                    float y = (float)yv[r];
                    o[r] = (__bf16)((acc[mt][nt][r] + pb3[m + r]) * y + y);
                }
                *(bf16x4*)&Pt[nl][m] = o;
            }
        }
    }
    __syncthreads();

    // ---- gemm2: q = gelu(W1[256][128].p + pb1) -> Qt (aliases Bt+Pt) ----
    {
        f32x4 acc[2][2][4];   // [mh][mt][nt]
#pragma unroll
        for (int mh = 0; mh < 2; ++mh)
#pragma unroll
            for (int mt = 0; mt < 2; ++mt)
#pragma unroll
                for (int nt = 0; nt < 4; ++nt)
#pragma unroll
                    for (int r = 0; r < 4; ++r) acc[mh][mt][nt][r] = 0.f;
#pragma unroll
        for (int mh = 0; mh < 2; ++mh) {
#pragma unroll
            for (int k0 = 0; k0 < 128; k0 += 32) {
                {
                    int m = tid >> 1, ks = (tid & 1) * 16;
                    const __bf16* src = g_w + 65536 + (size_t)(mh * 128 + m) * 128 + k0 + ks;
                    *(bf16x8*)&Ws[m][ks]     = *(const bf16x8*)src;
                    *(bf16x8*)&Ws[m][ks + 8] = *(const bf16x8*)(src + 8);
                }
                __syncthreads();
                bf16x8 af[2], bfr[4];
#pragma unroll
                for (int mt = 0; mt < 2; ++mt)
                    af[mt] = *(const bf16x8*)&Ws[wid * 32 + mt * 16 + fr][kg];
#pragma unroll
                for (int nt = 0; nt < 4; ++nt)
                    bfr[nt] = *(const bf16x8*)&Pt[nt * 16 + fr][k0 + kg];
#pragma unroll
                for (int mt = 0; mt < 2; ++mt)
#pragma unroll
                    for (int nt = 0; nt < 4; ++nt)
                        acc[mh][mt][nt] = __builtin_amdgcn_mfma_f32_16x16x32_bf16(af[mt], bfr[nt], acc[mh][mt][nt], 0, 0, 0);
                __syncthreads();
            }
        }
        // Bt & Pt dead -> write Qt over the union
#pragma unroll
        for (int mh = 0; mh < 2; ++mh)
#pragma unroll
            for (int nt = 0; nt < 4; ++nt) {
                int nl = nt * 16 + fr;
#pragma unroll
                for (int mt = 0; mt < 2; ++mt) {
                    int m = mh * 128 + wid * 32 + mt * 16 + mrow;
                    bf16x4 o;
#pragma unroll
                    for (int r = 0; r < 4; ++r) {
                        float xx = acc[mh][mt][nt][r] + pb1[m + r];
                        o[r] = (__bf16)(0.5f * xx * (1.f + erff(xx * 0.70710678118f)));
                    }
                    *(bf16x4*)&Qt[nl][m] = o;
                }
            }
    }
    __syncthreads();

    // ---- gemm3: out = W2[128][256].q + pb2 + y1*sig  (NCHW f32 store) ----
    {
        f32x4 acc[2][4];
#pragma unroll
        for (int mt = 0; mt < 2; ++mt)
#pragma unroll
            for (int nt = 0; nt < 4; ++nt)
#pragma unroll
                for (int r = 0; r < 4; ++r) acc[mt][nt][r] = 0.f;
#pragma unroll
        for (int k0 = 0; k0 < 256; k0 += 32) {
            {
                int m = tid >> 1, ks = (tid & 1) * 16;
                const __bf16* src = g_w + 98304 + (size_t)m * 256 + k0 + ks;
                *(bf16x8*)&Ws[m][ks]     = *(const bf16x8*)src;
                *(bf16x8*)&Ws[m][ks + 8] = *(const bf16x8*)(src + 8);
            }
            __syncthreads();
            bf16x8 af[2], bfr[4];
#pragma unroll
            for (int mt = 0; mt < 2; ++mt)
                af[mt] = *(const bf16x8*)&Ws[wid * 32 + mt * 16 + fr][kg];
#pragma unroll
            for (int nt = 0; nt < 4; ++nt)
                bfr[nt] = *(const bf16x8*)&Qt[nt * 16 + fr][k0 + kg];
#pragma unroll
            for (int mt = 0; mt < 2; ++mt)
#pragma unroll
                for (int nt = 0; nt < 4; ++nt)
                    acc[mt][nt] = __builtin_amdgcn_mfma_f32_16x16x32_bf16(af[mt], bfr[nt], acc[mt][nt], 0, 0, 0);
            __syncthreads();
        }
#pragma unroll
        for (int nt = 0; nt < 4; ++nt) {
            int hw = hw0 + nt * 16 + fr;
            size_t pbase = (size_t)(n0 + nt * 16 + fr) * 128;
#pragma unroll
            for (int mt = 0; mt < 2; ++mt) {
                int m = wid * 32 + mt * 16 + mrow;
                bf16x4 yv = *(const bf16x4*)&g_y1[pbase + m];
                bf16x4 sv = *(const bf16x4*)&g_Z[pbase + m];
#pragma unroll
                for (int r = 0; r < 4; ++r) {
                    out[(size_t)(b * 128 + m + r) * kHW + hw] =
                        acc[mt][nt][r] + pb2[m + r] + (float)yv[r] * (float)sv[r];
                }
            }
        }
    }
}

// ---------------------------------------------------------------------------
extern "C" void kernel_launch(void* const* d_in, const int* in_sizes, int n_in,
                              void* d_out, int out_size, void* d_ws, size_t ws_size,
                              hipStream_t stream)
{
    const float* x    = (const float*)d_in[0];
    const float* d1w  = (const float*)d_in[1];
    const float* d1b  = (const float*)d_in[2];
    const float* d4w  = (const float*)d_in[3];
    const float* d4b  = (const float*)d_in[4];
    const float* pa   = (const float*)d_in[5];
    const float* f1w1 = (const float*)d_in[6];
    const float* f1b1 = (const float*)d_in[7];
    const float* f1w2 = (const float*)d_in[8];
    const float* f1b2 = (const float*)d_in[9];
    const float* f2w1 = (const float*)d_in[10];
    const float* f2b1 = (const float*)d_in[11];
    const float* f2w2 = (const float*)d_in[12];
    const float* f2b2 = (const float*)d_in[13];
    const float* pw1  = (const float*)d_in[14];
    const float* pb1  = (const float*)d_in[15];
    const float* pw2  = (const float*)d_in[16];
    const float* pb2  = (const float*)d_in[17];
    const float* pw3  = (const float*)d_in[18];
    const float* pb3  = (const float*)d_in[19];
    float* out = (float*)d_out;

    k_prepw<<<672, 256, 0, stream>>>(f1w1, f1w2, f2w1, f2w2, pw1, pw2, d1w, d4w, pw3);
    k_fused<<<1024, 256, 0, stream>>>(x, d1b, d4b, pa, f1b1, f1b2, f2b1, f2b2);
    k_scan<<<256, 256, 0, stream>>>();
    k_mega<<<1024, 256, 0, stream>>>(pb3, pb1, pb2, out);

    (void)in_sizes; (void)n_in; (void)d_ws; (void)ws_size; (void)out_size;
}

// Round 11
// 129.969 us; speedup vs baseline: 14.7688x; 1.0598x over previous
//
#include <hip/hip_runtime.h>

// MSSFM round 11 — r10 (137.7us, PASS) + weights direct global->VGPR.
//   * Ws LDS staging deleted everywhere: weight fragments are per-lane 16B
//     global loads inside the MFMA K-loops (weights are L2-resident and
//     identical across all blocks). Removes ~2 barriers per 32-wide K-step
//     (44 -> ~8 in k_fused, ~40 -> ~6 in k_mega).
//   * r8's segfault was isolated to fast-exp INTRINSICS (r9); manual exp2
//     (r10) compiles — hoisting was never the trigger. Retained manual exp2.
//   * k_fused LDS 41.2KB, k_mega 34.8KB.
// HARD RULE: static LDS <= 64KB per kernel.

typedef __bf16 bf16x8 __attribute__((ext_vector_type(8)));
typedef __bf16 bf16x4 __attribute__((ext_vector_type(4)));
typedef float  f32x4  __attribute__((ext_vector_type(4)));

constexpr int kHW = 16384;   // 128*128

__device__ __align__(16) __bf16 g_y1[8388608];   // NHWC bf16
__device__ __align__(16) __bf16 g_Z [8388608];   // Z, then sigmoid(y2)
__device__ __align__(16) __bf16 g_F [8388608];   // F
// g_w: f1w1@0 f1w2@16384 f2w1@32768 f2w2@49152 pw1@65536 pw2@98304
//      A1@131072[128][96] A4@143360[128][96] pw3@155648
__device__ __align__(16) __bf16 g_w [172032];

// 2^x, pure arithmetic (r10-validated; exp intrinsics segfault this clang).
__device__ __forceinline__ float fast_exp2(float x)
{
    x = fminf(fmaxf(x, -125.f), 125.f);
    float n = floorf(x);
    float f = x - n;   // [0,1)
    float p = 1.f + f * (0.69314718f + f * (0.24022651f + f * (0.05550411f +
              f * (0.00961813f + f * 0.00133336f))));
    return __int_as_float(((int)n + 127) << 23) * p;
}
__device__ __forceinline__ float fast_tanh(float x)
{
    return 1.f - 2.f / (fast_exp2(2.88539008f * x) + 1.f);
}
__device__ __forceinline__ float fast_sig(float x)
{
    return 1.f / (1.f + fast_exp2(-1.44269504f * x));
}

// ---------------- pack weights to bf16 --------------------------------------
__global__ __launch_bounds__(256) void k_prepw(
    const float* __restrict__ f1w1, const float* __restrict__ f1w2,
    const float* __restrict__ f2w1, const float* __restrict__ f2w2,
    const float* __restrict__ pw1, const float* __restrict__ pw2,
    const float* __restrict__ d1w, const float* __restrict__ d4w,
    const float* __restrict__ pw3)
{
    int idx = blockIdx.x * 256 + threadIdx.x;  // 172032
    float v;
    if (idx < 16384)        v = f1w1[idx];
    else if (idx < 32768)   v = f1w2[idx - 16384];
    else if (idx < 49152)   v = f2w1[idx - 32768];
    else if (idx < 65536)   v = f2w2[idx - 49152];
    else if (idx < 98304)   v = pw1[idx - 65536];
    else if (idx < 131072)  v = pw2[idx - 98304];
    else if (idx < 155648) {
        // A1/A4: [128 c][96 k], k = tap*8+s (tap=kh*3+kw), taps 9..11 zero
        int r = idx - 131072;
        const float* src = d1w;
        if (r >= 12288) { r -= 12288; src = d4w; }
        int c = r / 96, k = r - c * 96;
        int tap = k >> 3, s = k & 7;
        v = (tap < 9) ? src[c * 72 + s * 9 + tap] : 0.f;
    } else                  v = pw3[idx - 155648];
    g_w[idx] = (__bf16)v;
}

// ---------------- 128x128 MFMA GEMM step, weights direct from global --------
// ACT: 0 tanh, 1 sigmoid. Output to LDS (Tdst) or NHWC bf16 global (gdst).
// NO internal barriers — callers sync around Bsrc/Tdst hazards.
template <int ACT>
__device__ void gemm_step(const __bf16 (*__restrict__ Bsrc)[136],
                          const __bf16* __restrict__ Wg,
                          const float* __restrict__ bias,
                          __bf16 (*__restrict__ Tdst)[136],
                          __bf16* __restrict__ gdst, int n0)
{
    const int tid = threadIdx.x;
    const int lane = tid & 63, wid = tid >> 6;
    const int fr = lane & 15, kg = (lane >> 4) << 3, mrow = (lane >> 4) << 2;

    f32x4 acc[2][4];
#pragma unroll
    for (int mt = 0; mt < 2; ++mt)
#pragma unroll
        for (int nt = 0; nt < 4; ++nt)
#pragma unroll
            for (int r = 0; r < 4; ++r) acc[mt][nt][r] = 0.f;

#pragma unroll
    for (int k0 = 0; k0 < 128; k0 += 32) {
        bf16x8 af[2], bfr[4];
#pragma unroll
        for (int mt = 0; mt < 2; ++mt)
            af[mt] = *(const bf16x8*)&Wg[(size_t)(wid * 32 + mt * 16 + fr) * 128 + k0 + kg];
#pragma unroll
        for (int nt = 0; nt < 4; ++nt)
            bfr[nt] = *(const bf16x8*)&Bsrc[nt * 16 + fr][k0 + kg];
#pragma unroll
        for (int mt = 0; mt < 2; ++mt)
#pragma unroll
            for (int nt = 0; nt < 4; ++nt)
                acc[mt][nt] = __builtin_amdgcn_mfma_f32_16x16x32_bf16(af[mt], bfr[nt], acc[mt][nt], 0, 0, 0);
    }

#pragma unroll
    for (int nt = 0; nt < 4; ++nt) {
        int nl = nt * 16 + fr;
#pragma unroll
        for (int mt = 0; mt < 2; ++mt) {
            int m = wid * 32 + mt * 16 + mrow;
            bf16x4 o;
#pragma unroll
            for (int r = 0; r < 4; ++r) {
                float v = acc[mt][nt][r] + bias[m + r];
                o[r] = (__bf16)((ACT == 0) ? fast_tanh(v) : fast_sig(v));
            }
            if (Tdst) *(bf16x4*)&Tdst[nl][m] = o;
            else      *(bf16x4*)&gdst[(size_t)(n0 + nl) * 128 + m] = o;
        }
    }
}

// ---------------- fused: DPB conv (im2col MFMA) + prescan (y1->Z,F) ---------
__global__ __launch_bounds__(256) void k_fused(
    const float* __restrict__ x, const float* __restrict__ d1b,
    const float* __restrict__ d4b, const float* __restrict__ pa,
    const float* __restrict__ f1b1, const float* __restrict__ f1b2,
    const float* __restrict__ f2b1, const float* __restrict__ f2b2)
{
    __shared__ __bf16 patch[5][80][8];   //  6400 B
    __shared__ __bf16 Bt[64][136];       // 17408 B (y1 tile)
    __shared__ __bf16 Tt[64][136];       // 17408 B -> 41216 B total

    const int tid = threadIdx.x;
    const int n0 = blockIdx.x * 64;            // global pixel base
    const int b = n0 >> 14, hw0 = n0 & 16383;
    const int h = hw0 >> 7, w0 = hw0 & 127;

    // ---- stage x patch: rows {h-7,h-1,h,h+1,h+7} x cols [w0-7, w0+70] ------
    const int roff[5] = {-7, -1, 0, 1, 7};
    for (int t = tid; t < 400; t += 256) {
        int rs = t / 80, c = t - rs * 80;
        int row = h + roff[rs], wc = w0 + c - 7;
        bf16x8 v;
#pragma unroll
        for (int s = 0; s < 8; ++s) v[s] = (__bf16)0.f;
        if ((unsigned)row < 128u && (unsigned)wc < 128u && c < 78) {
#pragma unroll
            for (int s = 0; s < 8; ++s)
                v[s] = (__bf16)x[(size_t)(b * 8 + s) * kHW + row * 128 + wc];
        }
        *(bf16x8*)&patch[rs][c][0] = v;
    }

    const int lane = tid & 63, wid = tid >> 6;
    const int fr = lane & 15, kg = (lane >> 4) << 3, mrow = (lane >> 4) << 2;

    f32x4 acc1[2][4], acc4[2][4];
#pragma unroll
    for (int mt = 0; mt < 2; ++mt)
#pragma unroll
        for (int nt = 0; nt < 4; ++nt)
#pragma unroll
            for (int r = 0; r < 4; ++r) { acc1[mt][nt][r] = 0.f; acc4[mt][nt][r] = 0.f; }

    __syncthreads();   // patch ready

#pragma unroll
    for (int cv = 0; cv < 2; ++cv) {
        const __bf16* Ag = g_w + (cv ? 143360 : 131072);
#pragma unroll
        for (int k0 = 0; k0 < 96; k0 += 32) {
            bf16x8 af[2], bfr[4];
#pragma unroll
            for (int mt = 0; mt < 2; ++mt)
                af[mt] = *(const bf16x8*)&Ag[(size_t)(wid * 32 + mt * 16 + fr) * 96 + k0 + kg];
            int tap = (k0 + kg) >> 3;   // uniform within a 16-lane group
#pragma unroll
            for (int nt = 0; nt < 4; ++nt) {
                bf16x8 bv;
#pragma unroll
                for (int i = 0; i < 8; ++i) bv[i] = (__bf16)0.f;
                if (tap < 9) {
                    int dh = tap / 3 - 1, dw = tap % 3 - 1;
                    int rowsel = cv ? (dh + 1) * 2 : dh + 2;
                    int col = nt * 16 + fr + dw * (cv ? 7 : 1) + 7;
                    bv = *(const bf16x8*)&patch[rowsel][col][0];
                }
                bfr[nt] = bv;
            }
            if (cv == 0) {
#pragma unroll
                for (int mt = 0; mt < 2; ++mt)
#pragma unroll
                    for (int nt = 0; nt < 4; ++nt)
                        acc1[mt][nt] = __builtin_amdgcn_mfma_f32_16x16x32_bf16(af[mt], bfr[nt], acc1[mt][nt], 0, 0, 0);
            } else {
#pragma unroll
                for (int mt = 0; mt < 2; ++mt)
#pragma unroll
                    for (int nt = 0; nt < 4; ++nt)
                        acc4[mt][nt] = __builtin_amdgcn_mfma_f32_16x16x32_bf16(af[mt], bfr[nt], acc4[mt][nt], 0, 0, 0);
            }
        }
    }

    // ---- epilogue: y1 = prelu + prelu -> Bt (LDS) + g_y1 (NHWC) ----
    const float pav = pa[0];
#pragma unroll
    for (int nt = 0; nt < 4; ++nt) {
        int nl = nt * 16 + fr;
#pragma unroll
        for (int mt = 0; mt < 2; ++mt) {
            int m = wid * 32 + mt * 16 + mrow;
            bf16x4 o;
#pragma unroll
            for (int r = 0; r < 4; ++r) {
                float v1 = acc1[mt][nt][r] + d1b[m + r];
                float v4 = acc4[mt][nt][r] + d4b[m + r];
                v1 = (v1 >= 0.f) ? v1 : pav * v1;
                v4 = (v4 >= 0.f) ? v4 : pav * v4;
                o[r] = (__bf16)(v1 + v4);
            }
            *(bf16x4*)&Bt[nl][m] = o;
            *(bf16x4*)&g_y1[(size_t)(n0 + nl) * 128 + m] = o;
        }
    }
    __syncthreads();

    // ---- prescan: Z = tanh(conv(tanh(conv))), F = sigmoid(...) ----
    gemm_step<0>(Bt, g_w,         f1b1, Tt, nullptr, n0);
    __syncthreads();
    gemm_step<0>(Tt, g_w + 16384, f1b2, nullptr, g_Z, n0);
    __syncthreads();
    gemm_step<0>(Bt, g_w + 32768, f2b1, Tt, nullptr, n0);
    __syncthreads();
    gemm_step<1>(Tt, g_w + 49152, f2b2, nullptr, g_F, n0);
}

// ---------------- SRU scan over H (bf16 NHWC); sigmoid in place -------------
__global__ __launch_bounds__(256) void k_scan()
{
    int b = blockIdx.x >> 6;
    int w = ((blockIdx.x & 63) << 1) + (threadIdx.x >> 7);
    int c = threadIdx.x & 127;
    size_t base = ((size_t)(b * kHW + w)) * 128 + c;   // element at h=0
    float st = 0.f;
    if (c < 64) {  // reverse scan: y2[h] = f[h]*y2[h+1] + (1-f[h])*z[h]
#pragma unroll 8
        for (int h = 127; h >= 0; --h) {
            size_t i = base + (size_t)h * 16384;
            float z = (float)g_Z[i], f = (float)g_F[i];
            st = f * st + (1.f - f) * z;
            g_Z[i] = (__bf16)fast_sig(st);
        }
    } else {       // forward scan (flip(reverse(flip)) algebra)
#pragma unroll 8
        for (int h = 0; h < 128; ++h) {
            size_t i = base + (size_t)h * 16384;
            float z = (float)g_Z[i], f = (float)g_F[i];
            st = f * st + (1.f - f) * z;
            g_Z[i] = (__bf16)fast_sig(st);
        }
    }
}

// ---------------- mega: pmul GEMM -> q GEMM (split-M) -> final GEMM ---------
__global__ __launch_bounds__(256) void k_mega(
    const float* __restrict__ pb3, const float* __restrict__ pb1,
    const float* __restrict__ pb2, float* __restrict__ out)
{
    __shared__ __align__(16) char U[34816];   // Bt | Pt ; Qt aliases both
    auto Bt = (__bf16 (*)[136])U;
    auto Pt = (__bf16 (*)[136])(U + 17408);
    auto Qt = (__bf16 (*)[264])U;

    const int tid = threadIdx.x;
    const int n0 = blockIdx.x * 64;
    const int b = n0 >> 14, hw0 = n0 & 16383;
    const int lane = tid & 63, wid = tid >> 6;
    const int fr = lane & 15, kg = (lane >> 4) << 3, mrow = (lane >> 4) << 2;

    // stage y1 tile (NHWC bf16, coalesced)
    {
        int n = tid >> 2, ks = (tid & 3) * 32;
        const __bf16* src = g_y1 + (size_t)(n0 + n) * 128 + ks;
        *(bf16x8*)&Bt[n][ks]      = *(const bf16x8*)src;
        *(bf16x8*)&Bt[n][ks + 8]  = *(const bf16x8*)(src + 8);
        *(bf16x8*)&Bt[n][ks + 16] = *(const bf16x8*)(src + 16);
        *(bf16x8*)&Bt[n][ks + 24] = *(const bf16x8*)(src + 24);
    }
    __syncthreads();

    // ---- gemm0: p = (W3.y1 + pb3)*y1 + y1 -> Pt ----
    {
        f32x4 acc[2][4];
#pragma unroll
        for (int mt = 0; mt < 2; ++mt)
#pragma unroll
            for (int nt = 0; nt < 4; ++nt)
#pragma unroll
                for (int r = 0; r < 4; ++r) acc[mt][nt][r] = 0.f;
#pragma unroll
        for (int k0 = 0; k0 < 128; k0 += 32) {
            bf16x8 af[2], bfr[4];
#pragma unroll
            for (int mt = 0; mt < 2; ++mt)
                af[mt] = *(const bf16x8*)&g_w[155648 + (size_t)(wid * 32 + mt * 16 + fr) * 128 + k0 + kg];
#pragma unroll
            for (int nt = 0; nt < 4; ++nt)
                bfr[nt] = *(const bf16x8*)&Bt[nt * 16 + fr][k0 + kg];
#pragma unroll
            for (int mt = 0; mt < 2; ++mt)
#pragma unroll
                for (int nt = 0; nt < 4; ++nt)
                    acc[mt][nt] = __builtin_amdgcn_mfma_f32_16x16x32_bf16(af[mt], bfr[nt], acc[mt][nt], 0, 0, 0);
        }
#pragma unroll
        for (int nt = 0; nt < 4; ++nt) {
            int nl = nt * 16 + fr;
#pragma unroll
            for (int mt = 0; mt < 2; ++mt) {
                int m = wid * 32 + mt * 16 + mrow;
                bf16x4 yv = *(const bf16x4*)&Bt[nl][m];
                bf16x4 o;
#pragma unroll
                for (int r = 0; r < 4; ++r) {
                    float y = (float)yv[r];
                    o[r] = (__bf16)((acc[mt][nt][r] + pb3[m + r]) * y + y);
                }
                *(bf16x4*)&Pt[nl][m] = o;
            }
        }
    }
    __syncthreads();

    // ---- gemm2: q = gelu(W1[256][128].p + pb1) -> Qt (aliases Bt+Pt) ----
    {
        f32x4 acc[2][2][4];   // [mh][mt][nt]
#pragma unroll
        for (int mh = 0; mh < 2; ++mh)
#pragma unroll
            for (int mt = 0; mt < 2; ++mt)
#pragma unroll
                for (int nt = 0; nt < 4; ++nt)
#pragma unroll
                    for (int r = 0; r < 4; ++r) acc[mh][mt][nt][r] = 0.f;
#pragma unroll
        for (int mh = 0; mh < 2; ++mh) {
#pragma unroll
            for (int k0 = 0; k0 < 128; k0 += 32) {
                bf16x8 af[2], bfr[4];
#pragma unroll
                for (int mt = 0; mt < 2; ++mt)
                    af[mt] = *(const bf16x8*)&g_w[65536 + (size_t)(mh * 128 + wid * 32 + mt * 16 + fr) * 128 + k0 + kg];
#pragma unroll
                for (int nt = 0; nt < 4; ++nt)
                    bfr[nt] = *(const bf16x8*)&Pt[nt * 16 + fr][k0 + kg];
#pragma unroll
                for (int mt = 0; mt < 2; ++mt)
#pragma unroll
                    for (int nt = 0; nt < 4; ++nt)
                        acc[mh][mt][nt] = __builtin_amdgcn_mfma_f32_16x16x32_bf16(af[mt], bfr[nt], acc[mh][mt][nt], 0, 0, 0);
            }
        }
        __syncthreads();   // all Pt reads done -> safe to overwrite as Qt
#pragma unroll
        for (int mh = 0; mh < 2; ++mh)
#pragma unroll
            for (int nt = 0; nt < 4; ++nt) {
                int nl = nt * 16 + fr;
#pragma unroll
                for (int mt = 0; mt < 2; ++mt) {
                    int m = mh * 128 + wid * 32 + mt * 16 + mrow;
                    bf16x4 o;
#pragma unroll
                    for (int r = 0; r < 4; ++r) {
                        float xx = acc[mh][mt][nt][r] + pb1[m + r];
                        o[r] = (__bf16)(0.5f * xx * (1.f + erff(xx * 0.70710678118f)));
                    }
                    *(bf16x4*)&Qt[nl][m] = o;
                }
            }
    }
    __syncthreads();

    // ---- gemm3: out = W2[128][256].q + pb2 + y1*sig  (NCHW f32 store) ----
    {
        f32x4 acc[2][4];
#pragma unroll
        for (int mt = 0; mt < 2; ++mt)
#pragma unroll
            for (int nt = 0; nt < 4; ++nt)
#pragma unroll
                for (int r = 0; r < 4; ++r) acc[mt][nt][r] = 0.f;
#pragma unroll
        for (int k0 = 0; k0 < 256; k0 += 32) {
            bf16x8 af[2], bfr[4];
#pragma unroll
            for (int mt = 0; mt < 2; ++mt)
                af[mt] = *(const bf16x8*)&g_w[98304 + (size_t)(wid * 32 + mt * 16 + fr) * 256 + k0 + kg];
#pragma unroll
            for (int nt = 0; nt < 4; ++nt)
                bfr[nt] = *(const bf16x8*)&Qt[nt * 16 + fr][k0 + kg];
#pragma unroll
            for (int mt = 0; mt < 2; ++mt)
#pragma unroll
                for (int nt = 0; nt < 4; ++nt)
                    acc[mt][nt] = __builtin_amdgcn_mfma_f32_16x16x32_bf16(af[mt], bfr[nt], acc[mt][nt], 0, 0, 0);
        }
#pragma unroll
        for (int nt = 0; nt < 4; ++nt) {
            int hw = hw0 + nt * 16 + fr;
            size_t pbase = (size_t)(n0 + nt * 16 + fr) * 128;
#pragma unroll
            for (int mt = 0; mt < 2; ++mt) {
                int m = wid * 32 + mt * 16 + mrow;
                bf16x4 yv = *(const bf16x4*)&g_y1[pbase + m];
                bf16x4 sv = *(const bf16x4*)&g_Z[pbase + m];
#pragma unroll
                for (int r = 0; r < 4; ++r) {
                    out[(size_t)(b * 128 + m + r) * kHW + hw] =
                        acc[mt][nt][r] + pb2[m + r] + (float)yv[r] * (float)sv[r];
                }
            }
        }
    }
}

// ---------------------------------------------------------------------------
extern "C" void kernel_launch(void* const* d_in, const int* in_sizes, int n_in,
                              void* d_out, int out_size, void* d_ws, size_t ws_size,
                              hipStream_t stream)
{
    const float* x    = (const float*)d_in[0];
    const float* d1w  = (const float*)d_in[1];
    const float* d1b  = (const float*)d_in[2];
    const float* d4w  = (const float*)d_in[3];
    const float* d4b  = (const float*)d_in[4];
    const float* pa   = (const float*)d_in[5];
    const float* f1w1 = (const float*)d_in[6];
    const float* f1b1 = (const float*)d_in[7];
    const float* f1w2 = (const float*)d_in[8];
    const float* f1b2 = (const float*)d_in[9];
    const float* f2w1 = (const float*)d_in[10];
    const float* f2b1 = (const float*)d_in[11];
    const float* f2w2 = (const float*)d_in[12];
    const float* f2b2 = (const float*)d_in[13];
    const float* pw1  = (const float*)d_in[14];
    const float* pb1  = (const float*)d_in[15];
    const float* pw2  = (const float*)d_in[16];
    const float* pb2  = (const float*)d_in[17];
    const float* pw3  = (const float*)d_in[18];
    const float* pb3  = (const float*)d_in[19];
    float* out = (float*)d_out;

    k_prepw<<<672, 256, 0, stream>>>(f1w1, f1w2, f2w1, f2w2, pw1, pw2, d1w, d4w, pw3);
    k_fused<<<1024, 256, 0, stream>>>(x, d1b, d4b, pa, f1b1, f1b2, f2b1, f2b2);
    k_scan<<<256, 256, 0, stream>>>();
    k_mega<<<1024, 256, 0, stream>>>(pb3, pb1, pb2, out);

    (void)in_sizes; (void)n_in; (void)d_ws; (void)ws_size; (void)out_size;
}

// Round 12
// 118.926 us; speedup vs baseline: 16.1401x; 1.0929x over previous
//
#include <hip/hip_runtime.h>

// MSSFM round 12 — r11 (130.0us, PASS) + two independent changes:
//   1. k_fused prescan: 4 chained GEMMs -> 2 dual-branch phases (Z and F
//      branches computed concurrently with twin accumulators). Barriers
//      4->2, chain depth halved. LDS 58.6KB (2 blocks/CU).
//   2. k_mega: libm erff GELU -> tanh-form GELU via fast_tanh (validated
//      manual-exp2 path; exp INTRINSICS segfault this clang — r8/r9).
// HARD RULE: static LDS <= 64KB per kernel.

typedef __bf16 bf16x8 __attribute__((ext_vector_type(8)));
typedef __bf16 bf16x4 __attribute__((ext_vector_type(4)));
typedef float  f32x4  __attribute__((ext_vector_type(4)));

constexpr int kHW = 16384;   // 128*128

__device__ __align__(16) __bf16 g_y1[8388608];   // NHWC bf16
__device__ __align__(16) __bf16 g_Z [8388608];   // Z, then sigmoid(y2)
__device__ __align__(16) __bf16 g_F [8388608];   // F
// g_w: f1w1@0 f1w2@16384 f2w1@32768 f2w2@49152 pw1@65536 pw2@98304
//      A1@131072[128][96] A4@143360[128][96] pw3@155648
__device__ __align__(16) __bf16 g_w [172032];

// 2^x, pure arithmetic (r10-validated).
__device__ __forceinline__ float fast_exp2(float x)
{
    x = fminf(fmaxf(x, -125.f), 125.f);
    float n = floorf(x);
    float f = x - n;   // [0,1)
    float p = 1.f + f * (0.69314718f + f * (0.24022651f + f * (0.05550411f +
              f * (0.00961813f + f * 0.00133336f))));
    return __int_as_float(((int)n + 127) << 23) * p;
}
__device__ __forceinline__ float fast_tanh(float x)
{
    return 1.f - 2.f / (fast_exp2(2.88539008f * x) + 1.f);
}
__device__ __forceinline__ float fast_sig(float x)
{
    return 1.f / (1.f + fast_exp2(-1.44269504f * x));
}
__device__ __forceinline__ float fast_gelu(float x)
{
    return 0.5f * x * (1.f + fast_tanh(0.79788456f * (x + 0.044715f * x * x * x)));
}

// ---------------- pack weights to bf16 --------------------------------------
__global__ __launch_bounds__(256) void k_prepw(
    const float* __restrict__ f1w1, const float* __restrict__ f1w2,
    const float* __restrict__ f2w1, const float* __restrict__ f2w2,
    const float* __restrict__ pw1, const float* __restrict__ pw2,
    const float* __restrict__ d1w, const float* __restrict__ d4w,
    const float* __restrict__ pw3)
{
    int idx = blockIdx.x * 256 + threadIdx.x;  // 172032
    float v;
    if (idx < 16384)        v = f1w1[idx];
    else if (idx < 32768)   v = f1w2[idx - 16384];
    else if (idx < 49152)   v = f2w1[idx - 32768];
    else if (idx < 65536)   v = f2w2[idx - 49152];
    else if (idx < 98304)   v = pw1[idx - 65536];
    else if (idx < 131072)  v = pw2[idx - 98304];
    else if (idx < 155648) {
        // A1/A4: [128 c][96 k], k = tap*8+s (tap=kh*3+kw), taps 9..11 zero
        int r = idx - 131072;
        const float* src = d1w;
        if (r >= 12288) { r -= 12288; src = d4w; }
        int c = r / 96, k = r - c * 96;
        int tap = k >> 3, s = k & 7;
        v = (tap < 9) ? src[c * 72 + s * 9 + tap] : 0.f;
    } else                  v = pw3[idx - 155648];
    g_w[idx] = (__bf16)v;
}

// ---------------- fused: DPB conv + dual-branch prescan ---------------------
__global__ __launch_bounds__(256) void k_fused(
    const float* __restrict__ x, const float* __restrict__ d1b,
    const float* __restrict__ d4b, const float* __restrict__ pa,
    const float* __restrict__ f1b1, const float* __restrict__ f1b2,
    const float* __restrict__ f2b1, const float* __restrict__ f2b2)
{
    __shared__ __bf16 patch[5][80][8];   //  6400 B
    __shared__ __bf16 Bt[64][136];       // 17408 B (y1 tile)
    __shared__ __bf16 Tz[64][136];       // 17408 B
    __shared__ __bf16 Tf[64][136];       // 17408 B -> 58624 B total

    const int tid = threadIdx.x;
    const int n0 = blockIdx.x * 64;            // global pixel base
    const int b = n0 >> 14, hw0 = n0 & 16383;
    const int h = hw0 >> 7, w0 = hw0 & 127;

    // ---- stage x patch: rows {h-7,h-1,h,h+1,h+7} x cols [w0-7, w0+70] ------
    const int roff[5] = {-7, -1, 0, 1, 7};
    for (int t = tid; t < 400; t += 256) {
        int rs = t / 80, c = t - rs * 80;
        int row = h + roff[rs], wc = w0 + c - 7;
        bf16x8 v;
#pragma unroll
        for (int s = 0; s < 8; ++s) v[s] = (__bf16)0.f;
        if ((unsigned)row < 128u && (unsigned)wc < 128u && c < 78) {
#pragma unroll
            for (int s = 0; s < 8; ++s)
                v[s] = (__bf16)x[(size_t)(b * 8 + s) * kHW + row * 128 + wc];
        }
        *(bf16x8*)&patch[rs][c][0] = v;
    }

    const int lane = tid & 63, wid = tid >> 6;
    const int fr = lane & 15, kg = (lane >> 4) << 3, mrow = (lane >> 4) << 2;

    f32x4 acc1[2][4], acc4[2][4];
#pragma unroll
    for (int mt = 0; mt < 2; ++mt)
#pragma unroll
        for (int nt = 0; nt < 4; ++nt)
#pragma unroll
            for (int r = 0; r < 4; ++r) { acc1[mt][nt][r] = 0.f; acc4[mt][nt][r] = 0.f; }

    __syncthreads();   // patch ready

#pragma unroll
    for (int cv = 0; cv < 2; ++cv) {
        const __bf16* Ag = g_w + (cv ? 143360 : 131072);
#pragma unroll
        for (int k0 = 0; k0 < 96; k0 += 32) {
            bf16x8 af[2], bfr[4];
#pragma unroll
            for (int mt = 0; mt < 2; ++mt)
                af[mt] = *(const bf16x8*)&Ag[(size_t)(wid * 32 + mt * 16 + fr) * 96 + k0 + kg];
            int tap = (k0 + kg) >> 3;   // uniform within a 16-lane group
#pragma unroll
            for (int nt = 0; nt < 4; ++nt) {
                bf16x8 bv;
#pragma unroll
                for (int i = 0; i < 8; ++i) bv[i] = (__bf16)0.f;
                if (tap < 9) {
                    int dh = tap / 3 - 1, dw = tap % 3 - 1;
                    int rowsel = cv ? (dh + 1) * 2 : dh + 2;
                    int col = nt * 16 + fr + dw * (cv ? 7 : 1) + 7;
                    bv = *(const bf16x8*)&patch[rowsel][col][0];
                }
                bfr[nt] = bv;
            }
            if (cv == 0) {
#pragma unroll
                for (int mt = 0; mt < 2; ++mt)
#pragma unroll
                    for (int nt = 0; nt < 4; ++nt)
                        acc1[mt][nt] = __builtin_amdgcn_mfma_f32_16x16x32_bf16(af[mt], bfr[nt], acc1[mt][nt], 0, 0, 0);
            } else {
#pragma unroll
                for (int mt = 0; mt < 2; ++mt)
#pragma unroll
                    for (int nt = 0; nt < 4; ++nt)
                        acc4[mt][nt] = __builtin_amdgcn_mfma_f32_16x16x32_bf16(af[mt], bfr[nt], acc4[mt][nt], 0, 0, 0);
            }
        }
    }

    // ---- epilogue: y1 = prelu + prelu -> Bt (LDS) + g_y1 (NHWC) ----
    const float pav = pa[0];
#pragma unroll
    for (int nt = 0; nt < 4; ++nt) {
        int nl = nt * 16 + fr;
#pragma unroll
        for (int mt = 0; mt < 2; ++mt) {
            int m = wid * 32 + mt * 16 + mrow;
            bf16x4 o;
#pragma unroll
            for (int r = 0; r < 4; ++r) {
                float v1 = acc1[mt][nt][r] + d1b[m + r];
                float v4 = acc4[mt][nt][r] + d4b[m + r];
                v1 = (v1 >= 0.f) ? v1 : pav * v1;
                v4 = (v4 >= 0.f) ? v4 : pav * v4;
                o[r] = (__bf16)(v1 + v4);
            }
            *(bf16x4*)&Bt[nl][m] = o;
            *(bf16x4*)&g_y1[(size_t)(n0 + nl) * 128 + m] = o;
        }
    }
    __syncthreads();

    // ---- prescan phase 1 (dual): t1 = tanh(W11.y1+b), t2 = tanh(W21.y1+b) --
    {
        f32x4 az[2][4], afc[2][4];
#pragma unroll
        for (int mt = 0; mt < 2; ++mt)
#pragma unroll
            for (int nt = 0; nt < 4; ++nt)
#pragma unroll
                for (int r = 0; r < 4; ++r) { az[mt][nt][r] = 0.f; afc[mt][nt][r] = 0.f; }
#pragma unroll
        for (int k0 = 0; k0 < 128; k0 += 32) {
            bf16x8 wz[2], wf[2], bfr[4];
#pragma unroll
            for (int mt = 0; mt < 2; ++mt) {
                size_t rowoff = (size_t)(wid * 32 + mt * 16 + fr) * 128 + k0 + kg;
                wz[mt] = *(const bf16x8*)&g_w[rowoff];            // f1w1
                wf[mt] = *(const bf16x8*)&g_w[32768 + rowoff];    // f2w1
            }
#pragma unroll
            for (int nt = 0; nt < 4; ++nt)
                bfr[nt] = *(const bf16x8*)&Bt[nt * 16 + fr][k0 + kg];
#pragma unroll
            for (int mt = 0; mt < 2; ++mt)
#pragma unroll
                for (int nt = 0; nt < 4; ++nt) {
                    az[mt][nt]  = __builtin_amdgcn_mfma_f32_16x16x32_bf16(wz[mt], bfr[nt], az[mt][nt], 0, 0, 0);
                    afc[mt][nt] = __builtin_amdgcn_mfma_f32_16x16x32_bf16(wf[mt], bfr[nt], afc[mt][nt], 0, 0, 0);
                }
        }
#pragma unroll
        for (int nt = 0; nt < 4; ++nt) {
            int nl = nt * 16 + fr;
#pragma unroll
            for (int mt = 0; mt < 2; ++mt) {
                int m = wid * 32 + mt * 16 + mrow;
                bf16x4 oz, of;
#pragma unroll
                for (int r = 0; r < 4; ++r) {
                    oz[r] = (__bf16)fast_tanh(az[mt][nt][r] + f1b1[m + r]);
                    of[r] = (__bf16)fast_tanh(afc[mt][nt][r] + f2b1[m + r]);
                }
                *(bf16x4*)&Tz[nl][m] = oz;
                *(bf16x4*)&Tf[nl][m] = of;
            }
        }
    }
    __syncthreads();

    // ---- prescan phase 2 (dual): Z = tanh(W12.t1+b), F = sig(W22.t2+b) -----
    {
        f32x4 az[2][4], afc[2][4];
#pragma unroll
        for (int mt = 0; mt < 2; ++mt)
#pragma unroll
            for (int nt = 0; nt < 4; ++nt)
#pragma unroll
                for (int r = 0; r < 4; ++r) { az[mt][nt][r] = 0.f; afc[mt][nt][r] = 0.f; }
#pragma unroll
        for (int k0 = 0; k0 < 128; k0 += 32) {
            bf16x8 wz[2], wf[2], bz[4], bf[4];
#pragma unroll
            for (int mt = 0; mt < 2; ++mt) {
                size_t rowoff = (size_t)(wid * 32 + mt * 16 + fr) * 128 + k0 + kg;
                wz[mt] = *(const bf16x8*)&g_w[16384 + rowoff];    // f1w2
                wf[mt] = *(const bf16x8*)&g_w[49152 + rowoff];    // f2w2
            }
#pragma unroll
            for (int nt = 0; nt < 4; ++nt) {
                bz[nt] = *(const bf16x8*)&Tz[nt * 16 + fr][k0 + kg];
                bf[nt] = *(const bf16x8*)&Tf[nt * 16 + fr][k0 + kg];
            }
#pragma unroll
            for (int mt = 0; mt < 2; ++mt)
#pragma unroll
                for (int nt = 0; nt < 4; ++nt) {
                    az[mt][nt]  = __builtin_amdgcn_mfma_f32_16x16x32_bf16(wz[mt], bz[nt], az[mt][nt], 0, 0, 0);
                    afc[mt][nt] = __builtin_amdgcn_mfma_f32_16x16x32_bf16(wf[mt], bf[nt], afc[mt][nt], 0, 0, 0);
                }
        }
#pragma unroll
        for (int nt = 0; nt < 4; ++nt) {
            int nl = nt * 16 + fr;
#pragma unroll
            for (int mt = 0; mt < 2; ++mt) {
                int m = wid * 32 + mt * 16 + mrow;
                bf16x4 oz, of;
#pragma unroll
                for (int r = 0; r < 4; ++r) {
                    oz[r] = (__bf16)fast_tanh(az[mt][nt][r] + f1b2[m + r]);
                    of[r] = (__bf16)fast_sig(afc[mt][nt][r] + f2b2[m + r]);
                }
                *(bf16x4*)&g_Z[(size_t)(n0 + nl) * 128 + m] = oz;
                *(bf16x4*)&g_F[(size_t)(n0 + nl) * 128 + m] = of;
            }
        }
    }
}

// ---------------- SRU scan over H (bf16 NHWC); sigmoid in place -------------
__global__ __launch_bounds__(256) void k_scan()
{
    int b = blockIdx.x >> 6;
    int w = ((blockIdx.x & 63) << 1) + (threadIdx.x >> 7);
    int c = threadIdx.x & 127;
    size_t base = ((size_t)(b * kHW + w)) * 128 + c;   // element at h=0
    float st = 0.f;
    if (c < 64) {  // reverse scan: y2[h] = f[h]*y2[h+1] + (1-f[h])*z[h]
#pragma unroll 8
        for (int h = 127; h >= 0; --h) {
            size_t i = base + (size_t)h * 16384;
            float z = (float)g_Z[i], f = (float)g_F[i];
            st = f * st + (1.f - f) * z;
            g_Z[i] = (__bf16)fast_sig(st);
        }
    } else {       // forward scan (flip(reverse(flip)) algebra)
#pragma unroll 8
        for (int h = 0; h < 128; ++h) {
            size_t i = base + (size_t)h * 16384;
            float z = (float)g_Z[i], f = (float)g_F[i];
            st = f * st + (1.f - f) * z;
            g_Z[i] = (__bf16)fast_sig(st);
        }
    }
}

// ---------------- mega: pmul GEMM -> q GEMM (split-M) -> final GEMM ---------
__global__ __launch_bounds__(256) void k_mega(
    const float* __restrict__ pb3, const float* __restrict__ pb1,
    const float* __restrict__ pb2, float* __restrict__ out)
{
    __shared__ __align__(16) char U[34816];   // Bt | Pt ; Qt aliases both
    auto Bt = (__bf16 (*)[136])U;
    auto Pt = (__bf16 (*)[136])(U + 17408);
    auto Qt = (__bf16 (*)[264])U;

    const int tid = threadIdx.x;
    const int n0 = blockIdx.x * 64;
    const int b = n0 >> 14, hw0 = n0 & 16383;
    const int lane = tid & 63, wid = tid >> 6;
    const int fr = lane & 15, kg = (lane >> 4) << 3, mrow = (lane >> 4) << 2;

    // stage y1 tile (NHWC bf16, coalesced)
    {
        int n = tid >> 2, ks = (tid & 3) * 32;
        const __bf16* src = g_y1 + (size_t)(n0 + n) * 128 + ks;
        *(bf16x8*)&Bt[n][ks]      = *(const bf16x8*)src;
        *(bf16x8*)&Bt[n][ks + 8]  = *(const bf16x8*)(src + 8);
        *(bf16x8*)&Bt[n][ks + 16] = *(const bf16x8*)(src + 16);
        *(bf16x8*)&Bt[n][ks + 24] = *(const bf16x8*)(src + 24);
    }
    __syncthreads();

    // ---- gemm0: p = (W3.y1 + pb3)*y1 + y1 -> Pt ----
    {
        f32x4 acc[2][4];
#pragma unroll
        for (int mt = 0; mt < 2; ++mt)
#pragma unroll
            for (int nt = 0; nt < 4; ++nt)
#pragma unroll
                for (int r = 0; r < 4; ++r) acc[mt][nt][r] = 0.f;
#pragma unroll
        for (int k0 = 0; k0 < 128; k0 += 32) {
            bf16x8 af[2], bfr[4];
#pragma unroll
            for (int mt = 0; mt < 2; ++mt)
                af[mt] = *(const bf16x8*)&g_w[155648 + (size_t)(wid * 32 + mt * 16 + fr) * 128 + k0 + kg];
#pragma unroll
            for (int nt = 0; nt < 4; ++nt)
                bfr[nt] = *(const bf16x8*)&Bt[nt * 16 + fr][k0 + kg];
#pragma unroll
            for (int mt = 0; mt < 2; ++mt)
#pragma unroll
                for (int nt = 0; nt < 4; ++nt)
                    acc[mt][nt] = __builtin_amdgcn_mfma_f32_16x16x32_bf16(af[mt], bfr[nt], acc[mt][nt], 0, 0, 0);
        }
#pragma unroll
        for (int nt = 0; nt < 4; ++nt) {
            int nl = nt * 16 + fr;
#pragma unroll
            for (int mt = 0; mt < 2; ++mt) {
                int m = wid * 32 + mt * 16 + mrow;
                bf16x4 yv = *(const bf16x4*)&Bt[nl][m];
                bf16x4 o;
#pragma unroll
                for (int r = 0; r < 4; ++r) {
                    float y = (float)yv[r];
                    o[r] = (__bf16)((acc[mt][nt][r] + pb3[m + r]) * y + y);
                }
                *(bf16x4*)&Pt[nl][m] = o;
            }
        }
    }
    __syncthreads();

    // ---- gemm2: q = gelu(W1[256][128].p + pb1) -> Qt (aliases Bt+Pt) ----
    {
        f32x4 acc[2][2][4];   // [mh][mt][nt]
#pragma unroll
        for (int mh = 0; mh < 2; ++mh)
#pragma unroll
            for (int mt = 0; mt < 2; ++mt)
#pragma unroll
                for (int nt = 0; nt < 4; ++nt)
#pragma unroll
                    for (int r = 0; r < 4; ++r) acc[mh][mt][nt][r] = 0.f;
#pragma unroll
        for (int mh = 0; mh < 2; ++mh) {
#pragma unroll
            for (int k0 = 0; k0 < 128; k0 += 32) {
                bf16x8 af[2], bfr[4];
#pragma unroll
                for (int mt = 0; mt < 2; ++mt)
                    af[mt] = *(const bf16x8*)&g_w[65536 + (size_t)(mh * 128 + wid * 32 + mt * 16 + fr) * 128 + k0 + kg];
#pragma unroll
                for (int nt = 0; nt < 4; ++nt)
                    bfr[nt] = *(const bf16x8*)&Pt[nt * 16 + fr][k0 + kg];
#pragma unroll
                for (int mt = 0; mt < 2; ++mt)
#pragma unroll
                    for (int nt = 0; nt < 4; ++nt)
                        acc[mh][mt][nt] = __builtin_amdgcn_mfma_f32_16x16x32_bf16(af[mt], bfr[nt], acc[mh][mt][nt], 0, 0, 0);
            }
        }
        __syncthreads();   // all Pt reads done -> safe to overwrite as Qt
#pragma unroll
        for (int mh = 0; mh < 2; ++mh)
#pragma unroll
            for (int nt = 0; nt < 4; ++nt) {
                int nl = nt * 16 + fr;
#pragma unroll
                for (int mt = 0; mt < 2; ++mt) {
                    int m = mh * 128 + wid * 32 + mt * 16 + mrow;
                    bf16x4 o;
#pragma unroll
                    for (int r = 0; r < 4; ++r)
                        o[r] = (__bf16)fast_gelu(acc[mh][mt][nt][r] + pb1[m + r]);
                    *(bf16x4*)&Qt[nl][m] = o;
                }
            }
    }
    __syncthreads();

    // ---- gemm3: out = W2[128][256].q + pb2 + y1*sig  (NCHW f32 store) ----
    {
        f32x4 acc[2][4];
#pragma unroll
        for (int mt = 0; mt < 2; ++mt)
#pragma unroll
            for (int nt = 0; nt < 4; ++nt)
#pragma unroll
                for (int r = 0; r < 4; ++r) acc[mt][nt][r] = 0.f;
#pragma unroll
        for (int k0 = 0; k0 < 256; k0 += 32) {
            bf16x8 af[2], bfr[4];
#pragma unroll
            for (int mt = 0; mt < 2; ++mt)
                af[mt] = *(const bf16x8*)&g_w[98304 + (size_t)(wid * 32 + mt * 16 + fr) * 256 + k0 + kg];
#pragma unroll
            for (int nt = 0; nt < 4; ++nt)
                bfr[nt] = *(const bf16x8*)&Qt[nt * 16 + fr][k0 + kg];
#pragma unroll
            for (int mt = 0; mt < 2; ++mt)
#pragma unroll
                for (int nt = 0; nt < 4; ++nt)
                    acc[mt][nt] = __builtin_amdgcn_mfma_f32_16x16x32_bf16(af[mt], bfr[nt], acc[mt][nt], 0, 0, 0);
        }
#pragma unroll
        for (int nt = 0; nt < 4; ++nt) {
            int hw = hw0 + nt * 16 + fr;
            size_t pbase = (size_t)(n0 + nt * 16 + fr) * 128;
#pragma unroll
            for (int mt = 0; mt < 2; ++mt) {
                int m = wid * 32 + mt * 16 + mrow;
                bf16x4 yv = *(const bf16x4*)&g_y1[pbase + m];
                bf16x4 sv = *(const bf16x4*)&g_Z[pbase + m];
#pragma unroll
                for (int r = 0; r < 4; ++r) {
                    out[(size_t)(b * 128 + m + r) * kHW + hw] =
                        acc[mt][nt][r] + pb2[m + r] + (float)yv[r] * (float)sv[r];
                }
            }
        }
    }
}

// ---------------------------------------------------------------------------
extern "C" void kernel_launch(void* const* d_in, const int* in_sizes, int n_in,
                              void* d_out, int out_size, void* d_ws, size_t ws_size,
                              hipStream_t stream)
{
    const float* x    = (const float*)d_in[0];
    const float* d1w  = (const float*)d_in[1];
    const float* d1b  = (const float*)d_in[2];
    const float* d4w  = (const float*)d_in[3];
    const float* d4b  = (const float*)d_in[4];
    const float* pa   = (const float*)d_in[5];
    const float* f1w1 = (const float*)d_in[6];
    const float* f1b1 = (const float*)d_in[7];
    const float* f1w2 = (const float*)d_in[8];
    const float* f1b2 = (const float*)d_in[9];
    const float* f2w1 = (const float*)d_in[10];
    const float* f2b1 = (const float*)d_in[11];
    const float* f2w2 = (const float*)d_in[12];
    const float* f2b2 = (const float*)d_in[13];
    const float* pw1  = (const float*)d_in[14];
    const float* pb1  = (const float*)d_in[15];
    const float* pw2  = (const float*)d_in[16];
    const float* pb2  = (const float*)d_in[17];
    const float* pw3  = (const float*)d_in[18];
    const float* pb3  = (const float*)d_in[19];
    float* out = (float*)d_out;

    k_prepw<<<672, 256, 0, stream>>>(f1w1, f1w2, f2w1, f2w2, pw1, pw2, d1w, d4w, pw3);
    k_fused<<<1024, 256, 0, stream>>>(x, d1b, d4b, pa, f1b1, f1b2, f2b1, f2b2);
    k_scan<<<256, 256, 0, stream>>>();
    k_mega<<<1024, 256, 0, stream>>>(pb3, pb1, pb2, out);

    (void)in_sizes; (void)n_in; (void)d_ws; (void)ws_size; (void)out_size;
}

// Round 13
// 102.162 us; speedup vs baseline: 18.7885x; 1.1641x over previous
//
#include <hip/hip_runtime.h>

// MSSFM round 13 — r12 (118.9us, PASS) + ONE concept: hardware transcendental
// ops via INLINE ASM (v_exp_f32 / v_rcp_f32). r8/r9 segfaults were in clang's
// exp-intrinsic LOWERING; inline asm bypasses that path. tanh: 24 VALU ops
// (manual exp2 + precise div) -> 5 ops. sigmoid -> 4 ops. ~128 transcendentals
// per k_fused thread = the dominant VALU cost (r12: VALUBusy 43%, MfmaUtil 8%).
// Plus: epilogue bias loads vectorized f32x4.
// HARD RULE: static LDS <= 64KB per kernel.

typedef __bf16 bf16x8 __attribute__((ext_vector_type(8)));
typedef __bf16 bf16x4 __attribute__((ext_vector_type(4)));
typedef float  f32x4  __attribute__((ext_vector_type(4)));

constexpr int kHW = 16384;   // 128*128

__device__ __align__(16) __bf16 g_y1[8388608];   // NHWC bf16
__device__ __align__(16) __bf16 g_Z [8388608];   // Z, then sigmoid(y2)
__device__ __align__(16) __bf16 g_F [8388608];   // F
// g_w: f1w1@0 f1w2@16384 f2w1@32768 f2w2@49152 pw1@65536 pw2@98304
//      A1@131072[128][96] A4@143360[128][96] pw3@155648
__device__ __align__(16) __bf16 g_w [172032];

// hardware 2^x and 1/x (VOP1, ~4cy). Inline asm avoids the exp-builtin
// lowering path that segfaults this clang (r8/r9).
__device__ __forceinline__ float hw_exp2(float x)
{
    float r;
    asm("v_exp_f32 %0, %1" : "=v"(r) : "v"(x));
    return r;
}
__device__ __forceinline__ float hw_rcp(float x)
{
    float r;
    asm("v_rcp_f32 %0, %1" : "=v"(r) : "v"(x));
    return r;
}
// tanh(x) = 1 - 2/(2^(2x·log2e)+1): 5 ops, saturates (exp2->0/inf, rcp(inf)=0)
__device__ __forceinline__ float fast_tanh(float x)
{
    return 1.f - 2.f * hw_rcp(hw_exp2(2.88539008f * x) + 1.f);
}
__device__ __forceinline__ float fast_sig(float x)
{
    return hw_rcp(1.f + hw_exp2(-1.44269504f * x));
}
__device__ __forceinline__ float fast_gelu(float x)
{
    return 0.5f * x * (1.f + fast_tanh(0.79788456f * (x + 0.044715f * x * x * x)));
}

// ---------------- pack weights to bf16 --------------------------------------
__global__ __launch_bounds__(256) void k_prepw(
    const float* __restrict__ f1w1, const float* __restrict__ f1w2,
    const float* __restrict__ f2w1, const float* __restrict__ f2w2,
    const float* __restrict__ pw1, const float* __restrict__ pw2,
    const float* __restrict__ d1w, const float* __restrict__ d4w,
    const float* __restrict__ pw3)
{
    int idx = blockIdx.x * 256 + threadIdx.x;  // 172032
    float v;
    if (idx < 16384)        v = f1w1[idx];
    else if (idx < 32768)   v = f1w2[idx - 16384];
    else if (idx < 49152)   v = f2w1[idx - 32768];
    else if (idx < 65536)   v = f2w2[idx - 49152];
    else if (idx < 98304)   v = pw1[idx - 65536];
    else if (idx < 131072)  v = pw2[idx - 98304];
    else if (idx < 155648) {
        // A1/A4: [128 c][96 k], k = tap*8+s (tap=kh*3+kw), taps 9..11 zero
        int r = idx - 131072;
        const float* src = d1w;
        if (r >= 12288) { r -= 12288; src = d4w; }
        int c = r / 96, k = r - c * 96;
        int tap = k >> 3, s = k & 7;
        v = (tap < 9) ? src[c * 72 + s * 9 + tap] : 0.f;
    } else                  v = pw3[idx - 155648];
    g_w[idx] = (__bf16)v;
}

// ---------------- fused: DPB conv + dual-branch prescan ---------------------
__global__ __launch_bounds__(256) void k_fused(
    const float* __restrict__ x, const float* __restrict__ d1b,
    const float* __restrict__ d4b, const float* __restrict__ pa,
    const float* __restrict__ f1b1, const float* __restrict__ f1b2,
    const float* __restrict__ f2b1, const float* __restrict__ f2b2)
{
    __shared__ __bf16 patch[5][80][8];   //  6400 B
    __shared__ __bf16 Bt[64][136];       // 17408 B (y1 tile)
    __shared__ __bf16 Tz[64][136];       // 17408 B
    __shared__ __bf16 Tf[64][136];       // 17408 B -> 58624 B total

    const int tid = threadIdx.x;
    const int n0 = blockIdx.x * 64;            // global pixel base
    const int b = n0 >> 14, hw0 = n0 & 16383;
    const int h = hw0 >> 7, w0 = hw0 & 127;

    // ---- stage x patch: rows {h-7,h-1,h,h+1,h+7} x cols [w0-7, w0+70] ------
    const int roff[5] = {-7, -1, 0, 1, 7};
    for (int t = tid; t < 400; t += 256) {
        int rs = t / 80, c = t - rs * 80;
        int row = h + roff[rs], wc = w0 + c - 7;
        bf16x8 v;
#pragma unroll
        for (int s = 0; s < 8; ++s) v[s] = (__bf16)0.f;
        if ((unsigned)row < 128u && (unsigned)wc < 128u && c < 78) {
#pragma unroll
            for (int s = 0; s < 8; ++s)
                v[s] = (__bf16)x[(size_t)(b * 8 + s) * kHW + row * 128 + wc];
        }
        *(bf16x8*)&patch[rs][c][0] = v;
    }

    const int lane = tid & 63, wid = tid >> 6;
    const int fr = lane & 15, kg = (lane >> 4) << 3, mrow = (lane >> 4) << 2;

    f32x4 acc1[2][4], acc4[2][4];
#pragma unroll
    for (int mt = 0; mt < 2; ++mt)
#pragma unroll
        for (int nt = 0; nt < 4; ++nt)
#pragma unroll
            for (int r = 0; r < 4; ++r) { acc1[mt][nt][r] = 0.f; acc4[mt][nt][r] = 0.f; }

    __syncthreads();   // patch ready

#pragma unroll
    for (int cv = 0; cv < 2; ++cv) {
        const __bf16* Ag = g_w + (cv ? 143360 : 131072);
#pragma unroll
        for (int k0 = 0; k0 < 96; k0 += 32) {
            bf16x8 af[2], bfr[4];
#pragma unroll
            for (int mt = 0; mt < 2; ++mt)
                af[mt] = *(const bf16x8*)&Ag[(size_t)(wid * 32 + mt * 16 + fr) * 96 + k0 + kg];
            int tap = (k0 + kg) >> 3;   // uniform within a 16-lane group
#pragma unroll
            for (int nt = 0; nt < 4; ++nt) {
                bf16x8 bv;
#pragma unroll
                for (int i = 0; i < 8; ++i) bv[i] = (__bf16)0.f;
                if (tap < 9) {
                    int dh = tap / 3 - 1, dw = tap % 3 - 1;
                    int rowsel = cv ? (dh + 1) * 2 : dh + 2;
                    int col = nt * 16 + fr + dw * (cv ? 7 : 1) + 7;
                    bv = *(const bf16x8*)&patch[rowsel][col][0];
                }
                bfr[nt] = bv;
            }
            if (cv == 0) {
#pragma unroll
                for (int mt = 0; mt < 2; ++mt)
#pragma unroll
                    for (int nt = 0; nt < 4; ++nt)
                        acc1[mt][nt] = __builtin_amdgcn_mfma_f32_16x16x32_bf16(af[mt], bfr[nt], acc1[mt][nt], 0, 0, 0);
            } else {
#pragma unroll
                for (int mt = 0; mt < 2; ++mt)
#pragma unroll
                    for (int nt = 0; nt < 4; ++nt)
                        acc4[mt][nt] = __builtin_amdgcn_mfma_f32_16x16x32_bf16(af[mt], bfr[nt], acc4[mt][nt], 0, 0, 0);
            }
        }
    }

    // ---- epilogue: y1 = prelu + prelu -> Bt (LDS) + g_y1 (NHWC) ----
    const float pav = pa[0];
#pragma unroll
    for (int nt = 0; nt < 4; ++nt) {
        int nl = nt * 16 + fr;
#pragma unroll
        for (int mt = 0; mt < 2; ++mt) {
            int m = wid * 32 + mt * 16 + mrow;
            f32x4 b1v = *(const f32x4*)&d1b[m];
            f32x4 b4v = *(const f32x4*)&d4b[m];
            bf16x4 o;
#pragma unroll
            for (int r = 0; r < 4; ++r) {
                float v1 = acc1[mt][nt][r] + b1v[r];
                float v4 = acc4[mt][nt][r] + b4v[r];
                v1 = (v1 >= 0.f) ? v1 : pav * v1;
                v4 = (v4 >= 0.f) ? v4 : pav * v4;
                o[r] = (__bf16)(v1 + v4);
            }
            *(bf16x4*)&Bt[nl][m] = o;
            *(bf16x4*)&g_y1[(size_t)(n0 + nl) * 128 + m] = o;
        }
    }
    __syncthreads();

    // ---- prescan phase 1 (dual): t1 = tanh(W11.y1+b), t2 = tanh(W21.y1+b) --
    {
        f32x4 az[2][4], afc[2][4];
#pragma unroll
        for (int mt = 0; mt < 2; ++mt)
#pragma unroll
            for (int nt = 0; nt < 4; ++nt)
#pragma unroll
                for (int r = 0; r < 4; ++r) { az[mt][nt][r] = 0.f; afc[mt][nt][r] = 0.f; }
#pragma unroll
        for (int k0 = 0; k0 < 128; k0 += 32) {
            bf16x8 wz[2], wf[2], bfr[4];
#pragma unroll
            for (int mt = 0; mt < 2; ++mt) {
                size_t rowoff = (size_t)(wid * 32 + mt * 16 + fr) * 128 + k0 + kg;
                wz[mt] = *(const bf16x8*)&g_w[rowoff];            // f1w1
                wf[mt] = *(const bf16x8*)&g_w[32768 + rowoff];    // f2w1
            }
#pragma unroll
            for (int nt = 0; nt < 4; ++nt)
                bfr[nt] = *(const bf16x8*)&Bt[nt * 16 + fr][k0 + kg];
#pragma unroll
            for (int mt = 0; mt < 2; ++mt)
#pragma unroll
                for (int nt = 0; nt < 4; ++nt) {
                    az[mt][nt]  = __builtin_amdgcn_mfma_f32_16x16x32_bf16(wz[mt], bfr[nt], az[mt][nt], 0, 0, 0);
                    afc[mt][nt] = __builtin_amdgcn_mfma_f32_16x16x32_bf16(wf[mt], bfr[nt], afc[mt][nt], 0, 0, 0);
                }
        }
#pragma unroll
        for (int nt = 0; nt < 4; ++nt) {
            int nl = nt * 16 + fr;
#pragma unroll
            for (int mt = 0; mt < 2; ++mt) {
                int m = wid * 32 + mt * 16 + mrow;
                f32x4 bz = *(const f32x4*)&f1b1[m];
                f32x4 bfv = *(const f32x4*)&f2b1[m];
                bf16x4 oz, of;
#pragma unroll
                for (int r = 0; r < 4; ++r) {
                    oz[r] = (__bf16)fast_tanh(az[mt][nt][r] + bz[r]);
                    of[r] = (__bf16)fast_tanh(afc[mt][nt][r] + bfv[r]);
                }
                *(bf16x4*)&Tz[nl][m] = oz;
                *(bf16x4*)&Tf[nl][m] = of;
            }
        }
    }
    __syncthreads();

    // ---- prescan phase 2 (dual): Z = tanh(W12.t1+b), F = sig(W22.t2+b) -----
    {
        f32x4 az[2][4], afc[2][4];
#pragma unroll
        for (int mt = 0; mt < 2; ++mt)
#pragma unroll
            for (int nt = 0; nt < 4; ++nt)
#pragma unroll
                for (int r = 0; r < 4; ++r) { az[mt][nt][r] = 0.f; afc[mt][nt][r] = 0.f; }
#pragma unroll
        for (int k0 = 0; k0 < 128; k0 += 32) {
            bf16x8 wz[2], wf[2], bz[4], bf[4];
#pragma unroll
            for (int mt = 0; mt < 2; ++mt) {
                size_t rowoff = (size_t)(wid * 32 + mt * 16 + fr) * 128 + k0 + kg;
                wz[mt] = *(const bf16x8*)&g_w[16384 + rowoff];    // f1w2
                wf[mt] = *(const bf16x8*)&g_w[49152 + rowoff];    // f2w2
            }
#pragma unroll
            for (int nt = 0; nt < 4; ++nt) {
                bz[nt] = *(const bf16x8*)&Tz[nt * 16 + fr][k0 + kg];
                bf[nt] = *(const bf16x8*)&Tf[nt * 16 + fr][k0 + kg];
            }
#pragma unroll
            for (int mt = 0; mt < 2; ++mt)
#pragma unroll
                for (int nt = 0; nt < 4; ++nt) {
                    az[mt][nt]  = __builtin_amdgcn_mfma_f32_16x16x32_bf16(wz[mt], bz[nt], az[mt][nt], 0, 0, 0);
                    afc[mt][nt] = __builtin_amdgcn_mfma_f32_16x16x32_bf16(wf[mt], bf[nt], afc[mt][nt], 0, 0, 0);
                }
        }
#pragma unroll
        for (int nt = 0; nt < 4; ++nt) {
            int nl = nt * 16 + fr;
#pragma unroll
            for (int mt = 0; mt < 2; ++mt) {
                int m = wid * 32 + mt * 16 + mrow;
                f32x4 bz = *(const f32x4*)&f1b2[m];
                f32x4 bfv = *(const f32x4*)&f2b2[m];
                bf16x4 oz, of;
#pragma unroll
                for (int r = 0; r < 4; ++r) {
                    oz[r] = (__bf16)fast_tanh(az[mt][nt][r] + bz[r]);
                    of[r] = (__bf16)fast_sig(afc[mt][nt][r] + bfv[r]);
                }
                *(bf16x4*)&g_Z[(size_t)(n0 + nl) * 128 + m] = oz;
                *(bf16x4*)&g_F[(size_t)(n0 + nl) * 128 + m] = of;
            }
        }
    }
}

// ---------------- SRU scan over H (bf16 NHWC); sigmoid in place -------------
__global__ __launch_bounds__(256) void k_scan()
{
    int b = blockIdx.x >> 6;
    int w = ((blockIdx.x & 63) << 1) + (threadIdx.x >> 7);
    int c = threadIdx.x & 127;
    size_t base = ((size_t)(b * kHW + w)) * 128 + c;   // element at h=0
    float st = 0.f;
    if (c < 64) {  // reverse scan: y2[h] = f[h]*y2[h+1] + (1-f[h])*z[h]
#pragma unroll 8
        for (int h = 127; h >= 0; --h) {
            size_t i = base + (size_t)h * 16384;
            float z = (float)g_Z[i], f = (float)g_F[i];
            st = f * st + (1.f - f) * z;
            g_Z[i] = (__bf16)fast_sig(st);
        }
    } else {       // forward scan (flip(reverse(flip)) algebra)
#pragma unroll 8
        for (int h = 0; h < 128; ++h) {
            size_t i = base + (size_t)h * 16384;
            float z = (float)g_Z[i], f = (float)g_F[i];
            st = f * st + (1.f - f) * z;
            g_Z[i] = (__bf16)fast_sig(st);
        }
    }
}

// ---------------- mega: pmul GEMM -> q GEMM (split-M) -> final GEMM ---------
__global__ __launch_bounds__(256) void k_mega(
    const float* __restrict__ pb3, const float* __restrict__ pb1,
    const float* __restrict__ pb2, float* __restrict__ out)
{
    __shared__ __align__(16) char U[34816];   // Bt | Pt ; Qt aliases both
    auto Bt = (__bf16 (*)[136])U;
    auto Pt = (__bf16 (*)[136])(U + 17408);
    auto Qt = (__bf16 (*)[264])U;

    const int tid = threadIdx.x;
    const int n0 = blockIdx.x * 64;
    const int b = n0 >> 14, hw0 = n0 & 16383;
    const int lane = tid & 63, wid = tid >> 6;
    const int fr = lane & 15, kg = (lane >> 4) << 3, mrow = (lane >> 4) << 2;

    // stage y1 tile (NHWC bf16, coalesced)
    {
        int n = tid >> 2, ks = (tid & 3) * 32;
        const __bf16* src = g_y1 + (size_t)(n0 + n) * 128 + ks;
        *(bf16x8*)&Bt[n][ks]      = *(const bf16x8*)src;
        *(bf16x8*)&Bt[n][ks + 8]  = *(const bf16x8*)(src + 8);
        *(bf16x8*)&Bt[n][ks + 16] = *(const bf16x8*)(src + 16);
        *(bf16x8*)&Bt[n][ks + 24] = *(const bf16x8*)(src + 24);
    }
    __syncthreads();

    // ---- gemm0: p = (W3.y1 + pb3)*y1 + y1 -> Pt ----
    {
        f32x4 acc[2][4];
#pragma unroll
        for (int mt = 0; mt < 2; ++mt)
#pragma unroll
            for (int nt = 0; nt < 4; ++nt)
#pragma unroll
                for (int r = 0; r < 4; ++r) acc[mt][nt][r] = 0.f;
#pragma unroll
        for (int k0 = 0; k0 < 128; k0 += 32) {
            bf16x8 af[2], bfr[4];
#pragma unroll
            for (int mt = 0; mt < 2; ++mt)
                af[mt] = *(const bf16x8*)&g_w[155648 + (size_t)(wid * 32 + mt * 16 + fr) * 128 + k0 + kg];
#pragma unroll
            for (int nt = 0; nt < 4; ++nt)
                bfr[nt] = *(const bf16x8*)&Bt[nt * 16 + fr][k0 + kg];
#pragma unroll
            for (int mt = 0; mt < 2; ++mt)
#pragma unroll
                for (int nt = 0; nt < 4; ++nt)
                    acc[mt][nt] = __builtin_amdgcn_mfma_f32_16x16x32_bf16(af[mt], bfr[nt], acc[mt][nt], 0, 0, 0);
        }
#pragma unroll
        for (int nt = 0; nt < 4; ++nt) {
            int nl = nt * 16 + fr;
#pragma unroll
            for (int mt = 0; mt < 2; ++mt) {
                int m = wid * 32 + mt * 16 + mrow;
                f32x4 b3 = *(const f32x4*)&pb3[m];
                bf16x4 yv = *(const bf16x4*)&Bt[nl][m];
                bf16x4 o;
#pragma unroll
                for (int r = 0; r < 4; ++r) {
                    float y = (float)yv[r];
                    o[r] = (__bf16)((acc[mt][nt][r] + b3[r]) * y + y);
                }
                *(bf16x4*)&Pt[nl][m] = o;
            }
        }
    }
    __syncthreads();

    // ---- gemm2: q = gelu(W1[256][128].p + pb1) -> Qt (aliases Bt+Pt) ----
    {
        f32x4 acc[2][2][4];   // [mh][mt][nt]
#pragma unroll
        for (int mh = 0; mh < 2; ++mh)
#pragma unroll
            for (int mt = 0; mt < 2; ++mt)
#pragma unroll
                for (int nt = 0; nt < 4; ++nt)
#pragma unroll
                    for (int r = 0; r < 4; ++r) acc[mh][mt][nt][r] = 0.f;
#pragma unroll
        for (int mh = 0; mh < 2; ++mh) {
#pragma unroll
            for (int k0 = 0; k0 < 128; k0 += 32) {
                bf16x8 af[2], bfr[4];
#pragma unroll
                for (int mt = 0; mt < 2; ++mt)
                    af[mt] = *(const bf16x8*)&g_w[65536 + (size_t)(mh * 128 + wid * 32 + mt * 16 + fr) * 128 + k0 + kg];
#pragma unroll
                for (int nt = 0; nt < 4; ++nt)
                    bfr[nt] = *(const bf16x8*)&Pt[nt * 16 + fr][k0 + kg];
#pragma unroll
                for (int mt = 0; mt < 2; ++mt)
#pragma unroll
                    for (int nt = 0; nt < 4; ++nt)
                        acc[mh][mt][nt] = __builtin_amdgcn_mfma_f32_16x16x32_bf16(af[mt], bfr[nt], acc[mh][mt][nt], 0, 0, 0);
            }
        }
        __syncthreads();   // all Pt reads done -> safe to overwrite as Qt
#pragma unroll
        for (int mh = 0; mh < 2; ++mh)
#pragma unroll
            for (int nt = 0; nt < 4; ++nt) {
                int nl = nt * 16 + fr;
#pragma unroll
                for (int mt = 0; mt < 2; ++mt) {
                    int m = mh * 128 + wid * 32 + mt * 16 + mrow;
                    f32x4 b1 = *(const f32x4*)&pb1[m];
                    bf16x4 o;
#pragma unroll
                    for (int r = 0; r < 4; ++r)
                        o[r] = (__bf16)fast_gelu(acc[mh][mt][nt][r] + b1[r]);
                    *(bf16x4*)&Qt[nl][m] = o;
                }
            }
    }
    __syncthreads();

    // ---- gemm3: out = W2[128][256].q + pb2 + y1*sig  (NCHW f32 store) ----
    {
        f32x4 acc[2][4];
#pragma unroll
        for (int mt = 0; mt < 2; ++mt)
#pragma unroll
            for (int nt = 0; nt < 4; ++nt)
#pragma unroll
                for (int r = 0; r < 4; ++r) acc[mt][nt][r] = 0.f;
#pragma unroll
        for (int k0 = 0; k0 < 256; k0 += 32) {
            bf16x8 af[2], bfr[4];
#pragma unroll
            for (int mt = 0; mt < 2; ++mt)
                af[mt] = *(const bf16x8*)&g_w[98304 + (size_t)(wid * 32 + mt * 16 + fr) * 256 + k0 + kg];
#pragma unroll
            for (int nt = 0; nt < 4; ++nt)
                bfr[nt] = *(const bf16x8*)&Qt[nt * 16 + fr][k0 + kg];
#pragma unroll
            for (int mt = 0; mt < 2; ++mt)
#pragma unroll
                for (int nt = 0; nt < 4; ++nt)
                    acc[mt][nt] = __builtin_amdgcn_mfma_f32_16x16x32_bf16(af[mt], bfr[nt], acc[mt][nt], 0, 0, 0);
        }
#pragma unroll
        for (int nt = 0; nt < 4; ++nt) {
            int hw = hw0 + nt * 16 + fr;
            size_t pbase = (size_t)(n0 + nt * 16 + fr) * 128;
#pragma unroll
            for (int mt = 0; mt < 2; ++mt) {
                int m = wid * 32 + mt * 16 + mrow;
                f32x4 b2 = *(const f32x4*)&pb2[m];
                bf16x4 yv = *(const bf16x4*)&g_y1[pbase + m];
                bf16x4 sv = *(const bf16x4*)&g_Z[pbase + m];
#pragma unroll
                for (int r = 0; r < 4; ++r) {
                    out[(size_t)(b * 128 + m + r) * kHW + hw] =
                        acc[mt][nt][r] + b2[r] + (float)yv[r] * (float)sv[r];
                }
            }
        }
    }
}

// ---------------------------------------------------------------------------
extern "C" void kernel_launch(void* const* d_in, const int* in_sizes, int n_in,
                              void* d_out, int out_size, void* d_ws, size_t ws_size,
                              hipStream_t stream)
{
    const float* x    = (const float*)d_in[0];
    const float* d1w  = (const float*)d_in[1];
    const float* d1b  = (const float*)d_in[2];
    const float* d4w  = (const float*)d_in[3];
    const float* d4b  = (const float*)d_in[4];
    const float* pa   = (const float*)d_in[5];
    const float* f1w1 = (const float*)d_in[6];
    const float* f1b1 = (const float*)d_in[7];
    const float* f1w2 = (const float*)d_in[8];
    const float* f1b2 = (const float*)d_in[9];
    const float* f2w1 = (const float*)d_in[10];
    const float* f2b1 = (const float*)d_in[11];
    const float* f2w2 = (const float*)d_in[12];
    const float* f2b2 = (const float*)d_in[13];
    const float* pw1  = (const float*)d_in[14];
    const float* pb1  = (const float*)d_in[15];
    const float* pw2  = (const float*)d_in[16];
    const float* pb2  = (const float*)d_in[17];
    const float* pw3  = (const float*)d_in[18];
    const float* pb3  = (const float*)d_in[19];
    float* out = (float*)d_out;

    k_prepw<<<672, 256, 0, stream>>>(f1w1, f1w2, f2w1, f2w2, pw1, pw2, d1w, d4w, pw3);
    k_fused<<<1024, 256, 0, stream>>>(x, d1b, d4b, pa, f1b1, f1b2, f2b1, f2b2);
    k_scan<<<256, 256, 0, stream>>>();
    k_mega<<<1024, 256, 0, stream>>>(pb3, pb1, pb2, out);

    (void)in_sizes; (void)n_in; (void)d_ws; (void)ws_size; (void)out_size;
}

// Round 14
// 95.858 us; speedup vs baseline: 20.0242x; 1.0658x over previous
//
#include <hip/hip_runtime.h>

// MSSFM round 14 — r13 (102.2us, PASS) + two changes:
//   1. k_fused: patch (dead after conv) aliased with Tf (born in phase 1)
//      -> LDS 58.6KB -> 51KB -> 3 blocks/CU (was 2). Occupancy lever.
//   2. k_scan: Z,F interleaved into g_ZF[pixel][2c]={z,f} (written free in
//      k_fused phase-2 epilogue as one 16B store) -> scan loads ONE bf16x2
//      (4B/lane, 256B/wave) instead of two strided 2B scalars. Sigmoid out
//      to new g_S, read by k_mega.
// HARD RULE: static LDS <= 64KB per kernel. exp INTRINSICS segfault this
// clang (r8/r9) — hardware exp2/rcp via inline asm (r13-validated).

typedef __bf16 bf16x8 __attribute__((ext_vector_type(8)));
typedef __bf16 bf16x4 __attribute__((ext_vector_type(4)));
typedef __bf16 bf16x2 __attribute__((ext_vector_type(2)));
typedef float  f32x4  __attribute__((ext_vector_type(4)));

constexpr int kHW = 16384;   // 128*128

__device__ __align__(16) __bf16 g_y1[8388608];    // NHWC bf16
__device__ __align__(16) __bf16 g_ZF[16777216];   // [pixel][2c]={Z,F} interleaved
__device__ __align__(16) __bf16 g_S [8388608];    // sigmoid(y2), NHWC
// g_w: f1w1@0 f1w2@16384 f2w1@32768 f2w2@49152 pw1@65536 pw2@98304
//      A1@131072[128][96] A4@143360[128][96] pw3@155648
__device__ __align__(16) __bf16 g_w [172032];

// hardware 2^x and 1/x via inline asm (r13-validated; builtins segfault).
__device__ __forceinline__ float hw_exp2(float x)
{
    float r;
    asm("v_exp_f32 %0, %1" : "=v"(r) : "v"(x));
    return r;
}
__device__ __forceinline__ float hw_rcp(float x)
{
    float r;
    asm("v_rcp_f32 %0, %1" : "=v"(r) : "v"(x));
    return r;
}
__device__ __forceinline__ float fast_tanh(float x)
{
    return 1.f - 2.f * hw_rcp(hw_exp2(2.88539008f * x) + 1.f);
}
__device__ __forceinline__ float fast_sig(float x)
{
    return hw_rcp(1.f + hw_exp2(-1.44269504f * x));
}
__device__ __forceinline__ float fast_gelu(float x)
{
    return 0.5f * x * (1.f + fast_tanh(0.79788456f * (x + 0.044715f * x * x * x)));
}

// ---------------- pack weights to bf16 --------------------------------------
__global__ __launch_bounds__(256) void k_prepw(
    const float* __restrict__ f1w1, const float* __restrict__ f1w2,
    const float* __restrict__ f2w1, const float* __restrict__ f2w2,
    const float* __restrict__ pw1, const float* __restrict__ pw2,
    const float* __restrict__ d1w, const float* __restrict__ d4w,
    const float* __restrict__ pw3)
{
    int idx = blockIdx.x * 256 + threadIdx.x;  // 172032
    float v;
    if (idx < 16384)        v = f1w1[idx];
    else if (idx < 32768)   v = f1w2[idx - 16384];
    else if (idx < 49152)   v = f2w1[idx - 32768];
    else if (idx < 65536)   v = f2w2[idx - 49152];
    else if (idx < 98304)   v = pw1[idx - 65536];
    else if (idx < 131072)  v = pw2[idx - 98304];
    else if (idx < 155648) {
        // A1/A4: [128 c][96 k], k = tap*8+s (tap=kh*3+kw), taps 9..11 zero
        int r = idx - 131072;
        const float* src = d1w;
        if (r >= 12288) { r -= 12288; src = d4w; }
        int c = r / 96, k = r - c * 96;
        int tap = k >> 3, s = k & 7;
        v = (tap < 9) ? src[c * 72 + s * 9 + tap] : 0.f;
    } else                  v = pw3[idx - 155648];
    g_w[idx] = (__bf16)v;
}

// ---------------- fused: DPB conv + dual-branch prescan ---------------------
__global__ __launch_bounds__(256) void k_fused(
    const float* __restrict__ x, const float* __restrict__ d1b,
    const float* __restrict__ d4b, const float* __restrict__ pa,
    const float* __restrict__ f1b1, const float* __restrict__ f1b2,
    const float* __restrict__ f2b1, const float* __restrict__ f2b2)
{
    __shared__ __bf16 Bt[64][136];             // 17408 B (y1 tile)
    __shared__ __bf16 Tz[64][136];             // 17408 B
    __shared__ __align__(16) char U2[17408];   // patch[5][80][8] then Tf[64][136]
    auto patch = (__bf16 (*)[80][8])U2;        // 6400 B, dead after conv loop
    auto Tf    = (__bf16 (*)[136])U2;          // born in phase 1
    // total 52224 B -> 3 blocks/CU

    const int tid = threadIdx.x;
    const int n0 = blockIdx.x * 64;            // global pixel base
    const int b = n0 >> 14, hw0 = n0 & 16383;
    const int h = hw0 >> 7, w0 = hw0 & 127;

    // ---- stage x patch: rows {h-7,h-1,h,h+1,h+7} x cols [w0-7, w0+70] ------
    const int roff[5] = {-7, -1, 0, 1, 7};
    for (int t = tid; t < 400; t += 256) {
        int rs = t / 80, c = t - rs * 80;
        int row = h + roff[rs], wc = w0 + c - 7;
        bf16x8 v;
#pragma unroll
        for (int s = 0; s < 8; ++s) v[s] = (__bf16)0.f;
        if ((unsigned)row < 128u && (unsigned)wc < 128u && c < 78) {
#pragma unroll
            for (int s = 0; s < 8; ++s)
                v[s] = (__bf16)x[(size_t)(b * 8 + s) * kHW + row * 128 + wc];
        }
        *(bf16x8*)&patch[rs][c][0] = v;
    }

    const int lane = tid & 63, wid = tid >> 6;
    const int fr = lane & 15, kg = (lane >> 4) << 3, mrow = (lane >> 4) << 2;

    f32x4 acc1[2][4], acc4[2][4];
#pragma unroll
    for (int mt = 0; mt < 2; ++mt)
#pragma unroll
        for (int nt = 0; nt < 4; ++nt)
#pragma unroll
            for (int r = 0; r < 4; ++r) { acc1[mt][nt][r] = 0.f; acc4[mt][nt][r] = 0.f; }

    __syncthreads();   // patch ready

#pragma unroll
    for (int cv = 0; cv < 2; ++cv) {
        const __bf16* Ag = g_w + (cv ? 143360 : 131072);
#pragma unroll
        for (int k0 = 0; k0 < 96; k0 += 32) {
            bf16x8 af[2], bfr[4];
#pragma unroll
            for (int mt = 0; mt < 2; ++mt)
                af[mt] = *(const bf16x8*)&Ag[(size_t)(wid * 32 + mt * 16 + fr) * 96 + k0 + kg];
            int tap = (k0 + kg) >> 3;   // uniform within a 16-lane group
#pragma unroll
            for (int nt = 0; nt < 4; ++nt) {
                bf16x8 bv;
#pragma unroll
                for (int i = 0; i < 8; ++i) bv[i] = (__bf16)0.f;
                if (tap < 9) {
                    int dh = tap / 3 - 1, dw = tap % 3 - 1;
                    int rowsel = cv ? (dh + 1) * 2 : dh + 2;
                    int col = nt * 16 + fr + dw * (cv ? 7 : 1) + 7;
                    bv = *(const bf16x8*)&patch[rowsel][col][0];
                }
                bfr[nt] = bv;
            }
            if (cv == 0) {
#pragma unroll
                for (int mt = 0; mt < 2; ++mt)
#pragma unroll
                    for (int nt = 0; nt < 4; ++nt)
                        acc1[mt][nt] = __builtin_amdgcn_mfma_f32_16x16x32_bf16(af[mt], bfr[nt], acc1[mt][nt], 0, 0, 0);
            } else {
#pragma unroll
                for (int mt = 0; mt < 2; ++mt)
#pragma unroll
                    for (int nt = 0; nt < 4; ++nt)
                        acc4[mt][nt] = __builtin_amdgcn_mfma_f32_16x16x32_bf16(af[mt], bfr[nt], acc4[mt][nt], 0, 0, 0);
            }
        }
    }

    // ---- epilogue: y1 = prelu + prelu -> Bt (LDS) + g_y1 (NHWC) ----
    const float pav = pa[0];
#pragma unroll
    for (int nt = 0; nt < 4; ++nt) {
        int nl = nt * 16 + fr;
#pragma unroll
        for (int mt = 0; mt < 2; ++mt) {
            int m = wid * 32 + mt * 16 + mrow;
            f32x4 b1v = *(const f32x4*)&d1b[m];
            f32x4 b4v = *(const f32x4*)&d4b[m];
            bf16x4 o;
#pragma unroll
            for (int r = 0; r < 4; ++r) {
                float v1 = acc1[mt][nt][r] + b1v[r];
                float v4 = acc4[mt][nt][r] + b4v[r];
                v1 = (v1 >= 0.f) ? v1 : pav * v1;
                v4 = (v4 >= 0.f) ? v4 : pav * v4;
                o[r] = (__bf16)(v1 + v4);
            }
            *(bf16x4*)&Bt[nl][m] = o;
            *(bf16x4*)&g_y1[(size_t)(n0 + nl) * 128 + m] = o;
        }
    }
    __syncthreads();   // Bt ready; patch reads all done -> Tf may overwrite U2

    // ---- prescan phase 1 (dual): t1 = tanh(W11.y1+b), t2 = tanh(W21.y1+b) --
    {
        f32x4 az[2][4], afc[2][4];
#pragma unroll
        for (int mt = 0; mt < 2; ++mt)
#pragma unroll
            for (int nt = 0; nt < 4; ++nt)
#pragma unroll
                for (int r = 0; r < 4; ++r) { az[mt][nt][r] = 0.f; afc[mt][nt][r] = 0.f; }
#pragma unroll
        for (int k0 = 0; k0 < 128; k0 += 32) {
            bf16x8 wz[2], wf[2], bfr[4];
#pragma unroll
            for (int mt = 0; mt < 2; ++mt) {
                size_t rowoff = (size_t)(wid * 32 + mt * 16 + fr) * 128 + k0 + kg;
                wz[mt] = *(const bf16x8*)&g_w[rowoff];            // f1w1
                wf[mt] = *(const bf16x8*)&g_w[32768 + rowoff];    // f2w1
            }
#pragma unroll
            for (int nt = 0; nt < 4; ++nt)
                bfr[nt] = *(const bf16x8*)&Bt[nt * 16 + fr][k0 + kg];
#pragma unroll
            for (int mt = 0; mt < 2; ++mt)
#pragma unroll
                for (int nt = 0; nt < 4; ++nt) {
                    az[mt][nt]  = __builtin_amdgcn_mfma_f32_16x16x32_bf16(wz[mt], bfr[nt], az[mt][nt], 0, 0, 0);
                    afc[mt][nt] = __builtin_amdgcn_mfma_f32_16x16x32_bf16(wf[mt], bfr[nt], afc[mt][nt], 0, 0, 0);
                }
        }
#pragma unroll
        for (int nt = 0; nt < 4; ++nt) {
            int nl = nt * 16 + fr;
#pragma unroll
            for (int mt = 0; mt < 2; ++mt) {
                int m = wid * 32 + mt * 16 + mrow;
                f32x4 bz = *(const f32x4*)&f1b1[m];
                f32x4 bfv = *(const f32x4*)&f2b1[m];
                bf16x4 oz, of;
#pragma unroll
                for (int r = 0; r < 4; ++r) {
                    oz[r] = (__bf16)fast_tanh(az[mt][nt][r] + bz[r]);
                    of[r] = (__bf16)fast_tanh(afc[mt][nt][r] + bfv[r]);
                }
                *(bf16x4*)&Tz[nl][m] = oz;
                *(bf16x4*)&Tf[nl][m] = of;
            }
        }
    }
    __syncthreads();

    // ---- prescan phase 2 (dual): Z = tanh(W12.t1+b), F = sig(W22.t2+b) -----
    // interleaved store: g_ZF[pixel][2m..2m+7] = {z0,f0,z1,f1,z2,f2,z3,f3}
    {
        f32x4 az[2][4], afc[2][4];
#pragma unroll
        for (int mt = 0; mt < 2; ++mt)
#pragma unroll
            for (int nt = 0; nt < 4; ++nt)
#pragma unroll
                for (int r = 0; r < 4; ++r) { az[mt][nt][r] = 0.f; afc[mt][nt][r] = 0.f; }
#pragma unroll
        for (int k0 = 0; k0 < 128; k0 += 32) {
            bf16x8 wz[2], wf[2], bz[4], bf[4];
#pragma unroll
            for (int mt = 0; mt < 2; ++mt) {
                size_t rowoff = (size_t)(wid * 32 + mt * 16 + fr) * 128 + k0 + kg;
                wz[mt] = *(const bf16x8*)&g_w[16384 + rowoff];    // f1w2
                wf[mt] = *(const bf16x8*)&g_w[49152 + rowoff];    // f2w2
            }
#pragma unroll
            for (int nt = 0; nt < 4; ++nt) {
                bz[nt] = *(const bf16x8*)&Tz[nt * 16 + fr][k0 + kg];
                bf[nt] = *(const bf16x8*)&Tf[nt * 16 + fr][k0 + kg];
            }
#pragma unroll
            for (int mt = 0; mt < 2; ++mt)
#pragma unroll
                for (int nt = 0; nt < 4; ++nt) {
                    az[mt][nt]  = __builtin_amdgcn_mfma_f32_16x16x32_bf16(wz[mt], bz[nt], az[mt][nt], 0, 0, 0);
                    afc[mt][nt] = __builtin_amdgcn_mfma_f32_16x16x32_bf16(wf[mt], bf[nt], afc[mt][nt], 0, 0, 0);
                }
        }
#pragma unroll
        for (int nt = 0; nt < 4; ++nt) {
            int nl = nt * 16 + fr;
#pragma unroll
            for (int mt = 0; mt < 2; ++mt) {
                int m = wid * 32 + mt * 16 + mrow;
                f32x4 bz = *(const f32x4*)&f1b2[m];
                f32x4 bfv = *(const f32x4*)&f2b2[m];
                bf16x8 ozf;
#pragma unroll
                for (int r = 0; r < 4; ++r) {
                    ozf[2 * r]     = (__bf16)fast_tanh(az[mt][nt][r] + bz[r]);
                    ozf[2 * r + 1] = (__bf16)fast_sig(afc[mt][nt][r] + bfv[r]);
                }
                *(bf16x8*)&g_ZF[(size_t)(n0 + nl) * 256 + 2 * m] = ozf;
            }
        }
    }
}

// ---------------- SRU scan over H; ZF interleaved in, sigmoid -> g_S --------
__global__ __launch_bounds__(256) void k_scan()
{
    int b = blockIdx.x >> 6;
    int w = ((blockIdx.x & 63) << 1) + (threadIdx.x >> 7);
    int c = threadIdx.x & 127;
    size_t pix0 = (size_t)(b * kHW + w);   // pixel at h=0
    float st = 0.f;
    if (c < 64) {  // reverse scan: y2[h] = f[h]*y2[h+1] + (1-f[h])*z[h]
#pragma unroll 8
        for (int h = 127; h >= 0; --h) {
            size_t pix = pix0 + (size_t)h * 128;
            bf16x2 v = *(const bf16x2*)&g_ZF[pix * 256 + 2 * c];
            float z = (float)v[0], f = (float)v[1];
            st = f * st + (1.f - f) * z;
            g_S[pix * 128 + c] = (__bf16)fast_sig(st);
        }
    } else {       // forward scan (flip(reverse(flip)) algebra)
#pragma unroll 8
        for (int h = 0; h < 128; ++h) {
            size_t pix = pix0 + (size_t)h * 128;
            bf16x2 v = *(const bf16x2*)&g_ZF[pix * 256 + 2 * c];
            float z = (float)v[0], f = (float)v[1];
            st = f * st + (1.f - f) * z;
            g_S[pix * 128 + c] = (__bf16)fast_sig(st);
        }
    }
}

// ---------------- mega: pmul GEMM -> q GEMM (split-M) -> final GEMM ---------
__global__ __launch_bounds__(256) void k_mega(
    const float* __restrict__ pb3, const float* __restrict__ pb1,
    const float* __restrict__ pb2, float* __restrict__ out)
{
    __shared__ __align__(16) char U[34816];   // Bt | Pt ; Qt aliases both
    auto Bt = (__bf16 (*)[136])U;
    auto Pt = (__bf16 (*)[136])(U + 17408);
    auto Qt = (__bf16 (*)[264])U;

    const int tid = threadIdx.x;
    const int n0 = blockIdx.x * 64;
    const int b = n0 >> 14, hw0 = n0 & 16383;
    const int lane = tid & 63, wid = tid >> 6;
    const int fr = lane & 15, kg = (lane >> 4) << 3, mrow = (lane >> 4) << 2;

    // stage y1 tile (NHWC bf16, coalesced)
    {
        int n = tid >> 2, ks = (tid & 3) * 32;
        const __bf16* src = g_y1 + (size_t)(n0 + n) * 128 + ks;
        *(bf16x8*)&Bt[n][ks]      = *(const bf16x8*)src;
        *(bf16x8*)&Bt[n][ks + 8]  = *(const bf16x8*)(src + 8);
        *(bf16x8*)&Bt[n][ks + 16] = *(const bf16x8*)(src + 16);
        *(bf16x8*)&Bt[n][ks + 24] = *(const bf16x8*)(src + 24);
    }
    __syncthreads();

    // ---- gemm0: p = (W3.y1 + pb3)*y1 + y1 -> Pt ----
    {
        f32x4 acc[2][4];
#pragma unroll
        for (int mt = 0; mt < 2; ++mt)
#pragma unroll
            for (int nt = 0; nt < 4; ++nt)
#pragma unroll
                for (int r = 0; r < 4; ++r) acc[mt][nt][r] = 0.f;
#pragma unroll
        for (int k0 = 0; k0 < 128; k0 += 32) {
            bf16x8 af[2], bfr[4];
#pragma unroll
            for (int mt = 0; mt < 2; ++mt)
                af[mt] = *(const bf16x8*)&g_w[155648 + (size_t)(wid * 32 + mt * 16 + fr) * 128 + k0 + kg];
#pragma unroll
            for (int nt = 0; nt < 4; ++nt)
                bfr[nt] = *(const bf16x8*)&Bt[nt * 16 + fr][k0 + kg];
#pragma unroll
            for (int mt = 0; mt < 2; ++mt)
#pragma unroll
                for (int nt = 0; nt < 4; ++nt)
                    acc[mt][nt] = __builtin_amdgcn_mfma_f32_16x16x32_bf16(af[mt], bfr[nt], acc[mt][nt], 0, 0, 0);
        }
#pragma unroll
        for (int nt = 0; nt < 4; ++nt) {
            int nl = nt * 16 + fr;
#pragma unroll
            for (int mt = 0; mt < 2; ++mt) {
                int m = wid * 32 + mt * 16 + mrow;
                f32x4 b3 = *(const f32x4*)&pb3[m];
                bf16x4 yv = *(const bf16x4*)&Bt[nl][m];
                bf16x4 o;
#pragma unroll
                for (int r = 0; r < 4; ++r) {
                    float y = (float)yv[r];
                    o[r] = (__bf16)((acc[mt][nt][r] + b3[r]) * y + y);
                }
                *(bf16x4*)&Pt[nl][m] = o;
            }
        }
    }
    __syncthreads();

    // ---- gemm2: q = gelu(W1[256][128].p + pb1) -> Qt (aliases Bt+Pt) ----
    {
        f32x4 acc[2][2][4];   // [mh][mt][nt]
#pragma unroll
        for (int mh = 0; mh < 2; ++mh)
#pragma unroll
            for (int mt = 0; mt < 2; ++mt)
#pragma unroll
                for (int nt = 0; nt < 4; ++nt)
#pragma unroll
                    for (int r = 0; r < 4; ++r) acc[mh][mt][nt][r] = 0.f;
#pragma unroll
        for (int mh = 0; mh < 2; ++mh) {
#pragma unroll
            for (int k0 = 0; k0 < 128; k0 += 32) {
                bf16x8 af[2], bfr[4];
#pragma unroll
                for (int mt = 0; mt < 2; ++mt)
                    af[mt] = *(const bf16x8*)&g_w[65536 + (size_t)(mh * 128 + wid * 32 + mt * 16 + fr) * 128 + k0 + kg];
#pragma unroll
                for (int nt = 0; nt < 4; ++nt)
                    bfr[nt] = *(const bf16x8*)&Pt[nt * 16 + fr][k0 + kg];
#pragma unroll
                for (int mt = 0; mt < 2; ++mt)
#pragma unroll
                    for (int nt = 0; nt < 4; ++nt)
                        acc[mh][mt][nt] = __builtin_amdgcn_mfma_f32_16x16x32_bf16(af[mt], bfr[nt], acc[mh][mt][nt], 0, 0, 0);
            }
        }
        __syncthreads();   // all Pt reads done -> safe to overwrite as Qt
#pragma unroll
        for (int mh = 0; mh < 2; ++mh)
#pragma unroll
            for (int nt = 0; nt < 4; ++nt) {
                int nl = nt * 16 + fr;
#pragma unroll
                for (int mt = 0; mt < 2; ++mt) {
                    int m = mh * 128 + wid * 32 + mt * 16 + mrow;
                    f32x4 b1 = *(const f32x4*)&pb1[m];
                    bf16x4 o;
#pragma unroll
                    for (int r = 0; r < 4; ++r)
                        o[r] = (__bf16)fast_gelu(acc[mh][mt][nt][r] + b1[r]);
                    *(bf16x4*)&Qt[nl][m] = o;
                }
            }
    }
    __syncthreads();

    // ---- gemm3: out = W2[128][256].q + pb2 + y1*sig  (NCHW f32 store) ----
    {
        f32x4 acc[2][4];
#pragma unroll
        for (int mt = 0; mt < 2; ++mt)
#pragma unroll
            for (int nt = 0; nt < 4; ++nt)
#pragma unroll
                for (int r = 0; r < 4; ++r) acc[mt][nt][r] = 0.f;
#pragma unroll
        for (int k0 = 0; k0 < 256; k0 += 32) {
            bf16x8 af[2], bfr[4];
#pragma unroll
            for (int mt = 0; mt < 2; ++mt)
                af[mt] = *(const bf16x8*)&g_w[98304 + (size_t)(wid * 32 + mt * 16 + fr) * 256 + k0 + kg];
#pragma unroll
            for (int nt = 0; nt < 4; ++nt)
                bfr[nt] = *(const bf16x8*)&Qt[nt * 16 + fr][k0 + kg];
#pragma unroll
            for (int mt = 0; mt < 2; ++mt)
#pragma unroll
                for (int nt = 0; nt < 4; ++nt)
                    acc[mt][nt] = __builtin_amdgcn_mfma_f32_16x16x32_bf16(af[mt], bfr[nt], acc[mt][nt], 0, 0, 0);
        }
#pragma unroll
        for (int nt = 0; nt < 4; ++nt) {
            int hw = hw0 + nt * 16 + fr;
            size_t pbase = (size_t)(n0 + nt * 16 + fr) * 128;
#pragma unroll
            for (int mt = 0; mt < 2; ++mt) {
                int m = wid * 32 + mt * 16 + mrow;
                f32x4 b2 = *(const f32x4*)&pb2[m];
                bf16x4 yv = *(const bf16x4*)&g_y1[pbase + m];
                bf16x4 sv = *(const bf16x4*)&g_S[pbase + m];
#pragma unroll
                for (int r = 0; r < 4; ++r) {
                    out[(size_t)(b * 128 + m + r) * kHW + hw] =
                        acc[mt][nt][r] + b2[r] + (float)yv[r] * (float)sv[r];
                }
            }
        }
    }
}

// ---------------------------------------------------------------------------
extern "C" void kernel_launch(void* const* d_in, const int* in_sizes, int n_in,
                              void* d_out, int out_size, void* d_ws, size_t ws_size,
                              hipStream_t stream)
{
    const float* x    = (const float*)d_in[0];
    const float* d1w  = (const float*)d_in[1];
    const float* d1b  = (const float*)d_in[2];
    const float* d4w  = (const float*)d_in[3];
    const float* d4b  = (const float*)d_in[4];
    const float* pa   = (const float*)d_in[5];
    const float* f1w1 = (const float*)d_in[6];
    const float* f1b1 = (const float*)d_in[7];
    const float* f1w2 = (const float*)d_in[8];
    const float* f1b2 = (const float*)d_in[9];
    const float* f2w1 = (const float*)d_in[10];
    const float* f2b1 = (const float*)d_in[11];
    const float* f2w2 = (const float*)d_in[12];
    const float* f2b2 = (const float*)d_in[13];
    const float* pw1  = (const float*)d_in[14];
    const float* pb1  = (const float*)d_in[15];
    const float* pw2  = (const float*)d_in[16];
    const float* pb2  = (const float*)d_in[17];
    const float* pw3  = (const float*)d_in[18];
    const float* pb3  = (const float*)d_in[19];
    float* out = (float*)d_out;

    k_prepw<<<672, 256, 0, stream>>>(f1w1, f1w2, f2w1, f2w2, pw1, pw2, d1w, d4w, pw3);
    k_fused<<<1024, 256, 0, stream>>>(x, d1b, d4b, pa, f1b1, f1b2, f2b1, f2b2);
    k_scan<<<256, 256, 0, stream>>>();
    k_mega<<<1024, 256, 0, stream>>>(pb3, pb1, pb2, out);

    (void)in_sizes; (void)n_in; (void)d_ws; (void)ws_size; (void)out_size;
}